// Round 14
// baseline (171.044 us; speedup 1.0000x reference)
//
#include <hip/hip_runtime.h>
#include <hip/hip_bf16.h>

#define EMB 1024
#define NEXP 8
#define NH 1024
#define N_GU 2048
#define TOPK 2

// gate_up: 256x256 8-phase template
#define BMg 256
#define BNg 256
#define BKg 64
#define MAXT256 40

// down: proven R12 config
#define BM 128
#define BN 128
#define BK 64
#define KTILES 16
#define MAXT128 72

typedef __attribute__((ext_vector_type(4))) float f32x4;
typedef __attribute__((ext_vector_type(8))) short s16x8;
typedef __attribute__((ext_vector_type(4))) short s16x4;

typedef __attribute__((address_space(3))) unsigned int lds_u32;
typedef __attribute__((address_space(1))) const unsigned int glb_u32;

__device__ __forceinline__ void gl_lds16(const void* g, void* l) {
  __builtin_amdgcn_global_load_lds((glb_u32*)g, (lds_u32*)l, 16, 0, 0);
}

__device__ __forceinline__ unsigned short f2bf(float f) {
  union { float f; unsigned int u; } a; a.f = f;
  unsigned int u = a.u;
  unsigned int r = (u + 0x7FFFu + ((u >> 16) & 1u)) >> 16;
  return (unsigned short)r;
}

__device__ __forceinline__ float b2f(unsigned short h) {
  union { unsigned int u; float f; } a;
  a.u = ((unsigned int)h) << 16;
  return a.f;
}

// bijective chunked XCD swizzle (m204)
__device__ __forceinline__ int xcd_swz(int bid, int nwg) {
  int q = nwg >> 3, r = nwg & 7;
  int xcd = bid & 7, pos = bid >> 3;
  int base = (xcd < r) ? xcd * (q + 1) : r * (q + 1) + (xcd - r) * q;
  return base + pos;
}

// ---------------- fused router + fp32->bf16 conversion ----------------
__global__ void convert_router(const float* __restrict__ x, unsigned short* __restrict__ xb, int n4x,
                               const float* __restrict__ guw, unsigned short* __restrict__ guwb, int n4g,
                               const float* __restrict__ dw, unsigned short* __restrict__ dwb, int n4d,
                               const float* __restrict__ rw, const float* __restrict__ rb, int T,
                               int* __restrict__ tokE, float* __restrict__ tokW) {
  int nr = T / 4;
  if ((int)blockIdx.x < nr) {
    int gwid = blockIdx.x * 4 + (threadIdx.x >> 6);
    int lane = threadIdx.x & 63;
    if (gwid >= T) return;
    const float* h = x + (size_t)gwid * EMB;
    float hreg[16];
    #pragma unroll
    for (int i = 0; i < 16; ++i) hreg[i] = h[lane + 64 * i];
    float sc[NEXP];
    #pragma unroll
    for (int e = 0; e < NEXP; ++e) {
      const float* w = rw + e * EMB;
      float s = 0.f;
      #pragma unroll
      for (int i = 0; i < 16; ++i) s += hreg[i] * w[lane + 64 * i];
      #pragma unroll
      for (int off = 32; off > 0; off >>= 1) s += __shfl_xor(s, off);
      sc[e] = s + rb[e];
    }
    if (lane == 0) {
      int e0 = 0; float v0 = sc[0];
      #pragma unroll
      for (int e = 1; e < NEXP; ++e) if (sc[e] > v0) { v0 = sc[e]; e0 = e; }
      int e1 = -1; float v1 = -3.0e38f;
      #pragma unroll
      for (int e = 0; e < NEXP; ++e) { if (e == e0) continue; if (sc[e] > v1) { v1 = sc[e]; e1 = e; } }
      float ex = __expf(v1 - v0);
      float w0 = 1.f / (1.f + ex);
      float w1 = ex / (1.f + ex);
      tokE[gwid * 2] = e0; tokE[gwid * 2 + 1] = e1;
      tokW[gwid * 2] = w0; tokW[gwid * 2 + 1] = w1;
    }
  } else {
    int tot = n4x + n4g + n4d;
    int base = (blockIdx.x - nr) * blockDim.x + threadIdx.x;
    int stride = (gridDim.x - nr) * blockDim.x;
    for (int i = base; i < tot; i += stride) {
      const float* src; unsigned short* dst; int k;
      if (i < n4x) { src = x; dst = xb; k = i; }
      else if (i < n4x + n4g) { src = guw; dst = guwb; k = i - n4x; }
      else { src = dw; dst = dwb; k = i - n4x - n4g; }
      float4 v = ((const float4*)src)[k];
      s16x4 o;
      o[0] = (short)f2bf(v.x);
      o[1] = (short)f2bf(v.y);
      o[2] = (short)f2bf(v.z);
      o[3] = (short)f2bf(v.w);
      ((s16x4*)dst)[k] = o;
    }
  }
}

// ---------------- fused histogram + offsets + BOTH tile maps + scatter ----------------
__global__ void meta_scatter(const int* __restrict__ tokE, int A,
                             int* __restrict__ tm256, int* __restrict__ tm128,
                             int* __restrict__ rows, int* __restrict__ apos) {
  __shared__ int hist[NEXP];
  __shared__ int offs[NEXP];
  __shared__ int fill[NEXP];
  int t = threadIdx.x;
  if (t < NEXP) { hist[t] = 0; fill[t] = 0; }
  __syncthreads();
  for (int i = t; i < A; i += blockDim.x) atomicAdd(&hist[tokE[i]], 1);
  __syncthreads();
  if (t == 0) {
    int off = 0, nt2 = 0, nt1 = 0;
    for (int e = 0; e < NEXP; ++e) {
      offs[e] = off;
      int c = hist[e];
      int n2 = (c + BMg - 1) / BMg;
      for (int k = 0; k < n2; ++k) {
        tm256[1 + nt2 * 3 + 0] = e;
        tm256[1 + nt2 * 3 + 1] = off + k * BMg;
        tm256[1 + nt2 * 3 + 2] = off + c;
        nt2++;
      }
      int n1 = (c + BM - 1) / BM;
      for (int k = 0; k < n1; ++k) {
        tm128[1 + nt1 * 3 + 0] = e;
        tm128[1 + nt1 * 3 + 1] = off + k * BM;
        tm128[1 + nt1 * 3 + 2] = off + c;
        nt1++;
      }
      off += c;
    }
    tm256[0] = nt2;
    tm128[0] = nt1;
  }
  __syncthreads();
  for (int i = t; i < A; i += blockDim.x) {
    int e = tokE[i];
    int p = offs[e] + atomicAdd(&fill[e], 1);
    rows[p] = i >> 1;
    apos[i] = p;
  }
}

// ---------------- grouped GEMM 1: 256x256 8-phase counted-vmcnt (m201 template) ----------------
// Phase = {ds_read quadrant frags; issue 2 gl_lds; setprio(1) 16 MFMA setprio(0); [vmcnt]; barrier}.
// buf0: read ph0-3 (tile 2i), staged ph4-7 (tile 2i+2). buf1: staged ph0-3 (tile 2i+1), read ph4-7.
// Staging order per buffer: B0,B1,B2,B3,A0,A2,A1,A3 (one quarter per gl_lds).
// Per-wave outstanding: enter ph0 w/ 2 -> ph1-end 6 -> vmcnt(4) -> ph3-end 8 -> vmcnt(2) -> ... never 0.
#define VM4 asm volatile("s_waitcnt vmcnt(4)" ::: "memory")
#define VM2 asm volatile("s_waitcnt vmcnt(2)" ::: "memory")
#define NOW
#define PHASE(buf, mh, nh, LOADA, STAGE, WAIT) do {                                          \
  if (LOADA) {                                                                               \
    _Pragma("unroll")                                                                        \
    for (int mf = 0; mf < 4; ++mf) {                                                         \
      int rowa = wr * 128 + (mh) * 64 + mf * 16 + fr;                                        \
      af[mf][0] = *(const s16x8*)(&As[buf][rowa * BKg + ((q8) ^ rsw)]);                      \
      af[mf][1] = *(const s16x8*)(&As[buf][rowa * BKg + ((32 + q8) ^ rsw)]);                 \
    }                                                                                        \
  }                                                                                          \
  s16x8 bf[2][2];                                                                            \
  _Pragma("unroll")                                                                          \
  for (int j = 0; j < 2; ++j) {                                                              \
    int rowb = wc * 64 + ((nh) * 2 + j) * 16 + fr;                                           \
    bf[j][0] = *(const s16x8*)(&Bs[buf][rowb * BKg + ((q8) ^ rsw)]);                         \
    bf[j][1] = *(const s16x8*)(&Bs[buf][rowb * BKg + ((32 + q8) ^ rsw)]);                    \
  }                                                                                          \
  STAGE;                                                                                     \
  __builtin_amdgcn_s_setprio(1);                                                             \
  _Pragma("unroll")                                                                          \
  for (int mf = 0; mf < 4; ++mf)                                                             \
    _Pragma("unroll")                                                                        \
    for (int j = 0; j < 2; ++j) {                                                            \
      acc[(mh)*4+mf][(nh)*2+j] = __builtin_amdgcn_mfma_f32_16x16x32_bf16(af[mf][0], bf[j][0], acc[(mh)*4+mf][(nh)*2+j], 0, 0, 0); \
      acc[(mh)*4+mf][(nh)*2+j] = __builtin_amdgcn_mfma_f32_16x16x32_bf16(af[mf][1], bf[j][1], acc[(mh)*4+mf][(nh)*2+j], 0, 0, 0); \
    }                                                                                        \
  __builtin_amdgcn_s_setprio(0);                                                             \
  WAIT;                                                                                      \
  asm volatile("" ::: "memory");                                                             \
  __builtin_amdgcn_s_barrier();                                                              \
  asm volatile("" ::: "memory");                                                             \
} while (0)

__global__ __launch_bounds__(512, 2) void gemm_gate_up(
    const unsigned short* __restrict__ xb,
    const unsigned short* __restrict__ gub,
    const float* __restrict__ gu_bias,
    const int* __restrict__ rows,
    const int* __restrict__ tilemeta,
    unsigned short* __restrict__ hact) {
  __shared__ __align__(16) short As[2][BMg * BKg];   // 2 x 32 KB
  __shared__ __align__(16) short Bs[2][BNg * BKg];   // 2 x 32 KB  (128 KB total)
  int wg = xcd_swz(blockIdx.x, gridDim.x);
  int tileid = wg >> 3;          // n fast axis (N_GU/256 = 8)
  int n0 = (wg & 7) * BNg;
  int nt = tilemeta[0];
  if (tileid >= nt) return;
  int e    = tilemeta[1 + tileid * 3 + 0];
  int m0   = tilemeta[1 + tileid * 3 + 1];
  int mEnd = tilemeta[1 + tileid * 3 + 2];

  int t = threadIdx.x;
  int lane = t & 63;
  int wid = t >> 6;              // 0..7
  int wr = wid >> 2;             // 0..1 : rows wr*128
  int wc = wid & 3;              // 0..3 : cols wc*64

  // staging: quarter q = 64 rows; thread t -> row t>>3, chunk t&7; source pre-swizzled (rule #21)
  int srow = t >> 3;             // 0..63
  int schunk = t & 7;
  int scol = ((schunk ^ (srow & 7)) * 8);
  const unsigned short* gaQ[4];
  const unsigned short* gbQ[4];
  int dstQ[4];
  #pragma unroll
  for (int q = 0; q < 4; ++q) {
    int ai = m0 + q * 64 + srow; if (ai >= mEnd) ai = mEnd - 1;
    gaQ[q] = xb + (size_t)rows[ai] * EMB + scol;
    gbQ[q] = gub + ((size_t)e * N_GU + n0 + q * 64 + srow) * EMB + scol;
    dstQ[q] = (q * 64 + srow) * BKg + schunk * 8;
  }

  int fr = lane & 15;
  int q8 = (lane >> 4) * 8;
  int rsw = (fr & 7) << 3;

  f32x4 acc[8][4];
  #pragma unroll
  for (int i = 0; i < 8; ++i)
    #pragma unroll
    for (int j = 0; j < 4; ++j) acc[i][j] = (f32x4){0.f, 0.f, 0.f, 0.f};
  s16x8 af[4][2];

  #define SA(buf, q, kt) gl_lds16(gaQ[q] + (kt) * BKg, &As[buf][dstQ[q]])
  #define SB(buf, q, kt) gl_lds16(gbQ[q] + (kt) * BKg, &Bs[buf][dstQ[q]])

  // prologue: tile 0 -> buf0 (B0..B3, A0, A2, A1, A3); keep newest 2 in flight
  SB(0, 0, 0); SB(0, 1, 0); SB(0, 2, 0); SB(0, 3, 0);
  SA(0, 0, 0); SA(0, 2, 0); SA(0, 1, 0); SA(0, 3, 0);
  VM2;
  asm volatile("" ::: "memory");
  __builtin_amdgcn_s_barrier();
  asm volatile("" ::: "memory");

  for (int i = 0; i < KTILES / 2; ++i) {
    int t1 = 2 * i + 1;
    int t2 = 2 * i + 2;
    bool st = (t2 < KTILES);
    PHASE(0, 0, 0, true,  { SB(1, 0, t1); SB(1, 1, t1); }, NOW);
    PHASE(0, 0, 1, false, { SB(1, 2, t1); SB(1, 3, t1); }, VM4);
    PHASE(0, 1, 0, true,  { SA(1, 0, t1); SA(1, 2, t1); }, NOW);
    PHASE(0, 1, 1, false, { SA(1, 1, t1); SA(1, 3, t1); }, VM2);
    PHASE(1, 0, 0, true,  { if (st) { SB(0, 0, t2); SB(0, 1, t2); } }, NOW);
    PHASE(1, 0, 1, false, { if (st) { SB(0, 2, t2); SB(0, 3, t2); } }, VM4);
    PHASE(1, 1, 0, true,  { if (st) { SA(0, 0, t2); SA(0, 2, t2); } }, NOW);
    PHASE(1, 1, 1, false, { if (st) { SA(0, 1, t2); SA(0, 3, t2); } }, VM2);
  }

  // epilogue: bias + SwiGLU (pair even/odd N via shfl_xor 1) -> bf16 hact
  const float* bias_e = gu_bias + (size_t)e * N_GU;
  #pragma unroll
  for (int mi = 0; mi < 8; ++mi) {
    int rbase = m0 + wr * 128 + mi * 16 + ((lane >> 4) * 4);
    #pragma unroll
    for (int nf = 0; nf < 4; ++nf) {
      int n = n0 + wc * 64 + nf * 16 + fr;
      float v[4], o[4];
      #pragma unroll
      for (int r = 0; r < 4; ++r) v[r] = acc[mi][nf][r] + bias_e[n];
      #pragma unroll
      for (int r = 0; r < 4; ++r) o[r] = __shfl_xor(v[r], 1);
      if ((lane & 1) == 0) {
        int outc = n >> 1;
        #pragma unroll
        for (int r = 0; r < 4; ++r) {
          int pos = rbase + r;
          if (pos < mEnd) {
            float g = v[r], u = o[r];
            float gc = fminf(fmaxf(g, -7.f), 7.f);
            float uc = fminf(fmaxf(u, -7.f), 7.f);
            float sig = 1.f / (1.f + __expf(-1.702f * g));
            float act = gc * sig * (uc + 1.f);
            hact[(size_t)pos * NH + outc] = f2bf(act);
          }
        }
      }
    }
  }
}

// ---------------- grouped GEMM 2 (R12-proven 128x128): hact @ down_w^T -> y (bf16) ----------------
__global__ __launch_bounds__(256, 4) void gemm_down(
    const unsigned short* __restrict__ hact,
    const unsigned short* __restrict__ dwb,
    const int* __restrict__ tilemeta,
    unsigned short* __restrict__ y) {
  __shared__ __align__(16) short As[BM * BK];
  __shared__ __align__(16) short Bs[BN * BK];
  int wg = xcd_swz(blockIdx.x, gridDim.x);
  int tileid = wg >> 3;
  int n0 = (wg & 7) * BN;
  int nt = tilemeta[0];
  if (tileid >= nt) return;
  int e    = tilemeta[1 + tileid * 3 + 0];
  int m0   = tilemeta[1 + tileid * 3 + 1];
  int mEnd = tilemeta[1 + tileid * 3 + 2];

  int t = threadIdx.x;
  int lane = t & 63;
  int wid = t >> 6;
  int wr = wid >> 1, wc = wid & 1;

  int srow = lane >> 3;
  int scol = (((lane & 7) ^ (srow & 7)) * 8);
  const unsigned short* ga[4];
  const unsigned short* gb[4];
  int dstoff[4];
  #pragma unroll
  for (int q = 0; q < 4; ++q) {
    int rt = wid * 32 + q * 8 + srow;
    int ai = m0 + rt; if (ai >= mEnd) ai = mEnd - 1;
    ga[q] = hact + (size_t)ai * NH + scol;
    gb[q] = dwb + ((size_t)e * EMB + n0 + rt) * NH + scol;
    dstoff[q] = (wid * 32 + q * 8) * BK;
  }

  int fr = lane & 15;
  int q8 = (lane >> 4) * 8;
  int rsw = (fr & 7) << 3;

  f32x4 acc[4][4];
  #pragma unroll
  for (int i = 0; i < 4; ++i)
    #pragma unroll
    for (int j = 0; j < 4; ++j) acc[i][j] = (f32x4){0.f, 0.f, 0.f, 0.f};

  for (int tk = 0; tk < KTILES; ++tk) {
    int k0 = tk * BK;
    __syncthreads();
    #pragma unroll
    for (int q = 0; q < 4; ++q) {
      gl_lds16(ga[q] + k0, &As[dstoff[q]]);
      gl_lds16(gb[q] + k0, &Bs[dstoff[q]]);
    }
    __syncthreads();
    #pragma unroll
    for (int kk = 0; kk < BK; kk += 32) {
      s16x8 a[4], b[4];
      #pragma unroll
      for (int i = 0; i < 4; ++i)
        a[i] = *(const s16x8*)(&As[(wr * 64 + i * 16 + fr) * BK + ((kk + q8) ^ rsw)]);
      #pragma unroll
      for (int j = 0; j < 4; ++j)
        b[j] = *(const s16x8*)(&Bs[(wc * 64 + j * 16 + fr) * BK + ((kk + q8) ^ rsw)]);
      #pragma unroll
      for (int i = 0; i < 4; ++i)
        #pragma unroll
        for (int j = 0; j < 4; ++j)
          acc[i][j] = __builtin_amdgcn_mfma_f32_16x16x32_bf16(a[i], b[j], acc[i][j], 0, 0, 0);
    }
  }

  int rbase = m0 + wr * 64 + ((lane >> 4) * 4);
  #pragma unroll
  for (int i = 0; i < 4; ++i) {
    #pragma unroll
    for (int j = 0; j < 4; ++j) {
      int n = n0 + wc * 64 + j * 16 + fr;
      #pragma unroll
      for (int r = 0; r < 4; ++r) {
        int pos = rbase + i * 16 + r;
        if (pos < mEnd) y[(size_t)pos * EMB + n] = f2bf(acc[i][j][r]);
      }
    }
  }
}

// ---------------- final combine (bf16 y) ----------------
__global__ void combine_out(const unsigned short* __restrict__ y, const float* __restrict__ down_b,
                            const int* __restrict__ tokE, const float* __restrict__ tokW,
                            const int* __restrict__ apos, float* __restrict__ out, int T) {
  int i = blockIdx.x * blockDim.x + threadIdx.x;
  int tot = T * (EMB / 4);
  if (i >= tot) return;
  int tok = i >> 8;
  int c = i & 255;
  int e0 = tokE[tok * 2], e1 = tokE[tok * 2 + 1];
  float w0 = tokW[tok * 2], w1 = tokW[tok * 2 + 1];
  int p0 = apos[tok * 2], p1 = apos[tok * 2 + 1];
  s16x4 v0 = ((const s16x4*)(y + (size_t)p0 * EMB))[c];
  s16x4 v1 = ((const s16x4*)(y + (size_t)p1 * EMB))[c];
  float4 b0 = ((const float4*)(down_b + (size_t)e0 * EMB))[c];
  float4 b1 = ((const float4*)(down_b + (size_t)e1 * EMB))[c];
  float4 o;
  o.x = w0 * (b2f((unsigned short)v0[0]) + b0.x) + w1 * (b2f((unsigned short)v1[0]) + b1.x);
  o.y = w0 * (b2f((unsigned short)v0[1]) + b0.y) + w1 * (b2f((unsigned short)v1[1]) + b1.y);
  o.z = w0 * (b2f((unsigned short)v0[2]) + b0.z) + w1 * (b2f((unsigned short)v1[2]) + b1.z);
  o.w = w0 * (b2f((unsigned short)v0[3]) + b0.w) + w1 * (b2f((unsigned short)v1[3]) + b1.w);
  ((float4*)out)[i] = o;
}

extern "C" void kernel_launch(void* const* d_in, const int* in_sizes, int n_in,
                              void* d_out, int out_size, void* d_ws, size_t ws_size,
                              hipStream_t stream) {
  const float* x   = (const float*)d_in[0];
  const float* rw  = (const float*)d_in[1];
  const float* rb  = (const float*)d_in[2];
  const float* guw = (const float*)d_in[3];
  const float* gub = (const float*)d_in[4];
  const float* dw  = (const float*)d_in[5];
  const float* db  = (const float*)d_in[6];
  float* out = (float*)d_out;

  int T = in_sizes[0] / EMB;   // 4096
  int A = T * TOPK;            // 8192

  char* ws = (char*)d_ws;
  size_t off = 0;
  auto alloc = [&](size_t bytes) -> void* {
    void* p = ws + off;
    off = (off + bytes + 255) & ~((size_t)255);
    return p;
  };
  unsigned short* xb   = (unsigned short*)alloc((size_t)T * EMB * 2);
  unsigned short* guwb = (unsigned short*)alloc((size_t)NEXP * N_GU * EMB * 2);
  unsigned short* dwb  = (unsigned short*)alloc((size_t)NEXP * EMB * NH * 2);
  unsigned short* hact = (unsigned short*)alloc((size_t)A * NH * 2);
  unsigned short* y    = (unsigned short*)alloc((size_t)A * EMB * 2);
  int*   tokE    = (int*)alloc((size_t)A * 4);
  float* tokW    = (float*)alloc((size_t)A * 4);
  int*   apos    = (int*)alloc((size_t)A * 4);
  int*   rowsArr = (int*)alloc((size_t)A * 4);
  int*   tm256   = (int*)alloc((1 + MAXT256 * 3) * 4);
  int*   tm128   = (int*)alloc((1 + MAXT128 * 3) * 4);

  int n4x = T * EMB / 4;
  int n4g = NEXP * N_GU * EMB / 4;
  int n4d = NEXP * EMB * NH / 4;
  convert_router<<<T / 4 + 2048, 256, 0, stream>>>(x, xb, n4x, guw, guwb, n4g, dw, dwb, n4d,
                                                   rw, rb, T, tokE, tokW);

  meta_scatter<<<1, 1024, 0, stream>>>(tokE, A, tm256, tm128, rowsArr, apos);

  gemm_gate_up<<<MAXT256 * (N_GU / BNg), 512, 0, stream>>>(xb, guwb, gub, rowsArr, tm256, hact);
  gemm_down<<<MAXT128 * (EMB / BN), 256, 0, stream>>>(hact, dwb, tm128, y);

  combine_out<<<(T * EMB / 4 + 255) / 256, 256, 0, stream>>>(y, db, tokE, tokW, apos, out, T);
}

// Round 15
// 136.213 us; speedup vs baseline: 1.2557x; 1.2557x over previous
//
#include <hip/hip_runtime.h>
#include <hip/hip_bf16.h>

#define EMB 1024
#define NEXP 8
#define NH 1024
#define N_GU 2048
#define TOPK 2

#define BM 128
#define BN 128
#define BK 64
#define KTILES 16      // 1024 / 64
#define MAXTILES 72
#define GRID_GU (MAXTILES * 16)
#define CONV_BLKS 256

typedef __attribute__((ext_vector_type(4))) float f32x4;
typedef __attribute__((ext_vector_type(8))) short s16x8;
typedef __attribute__((ext_vector_type(4))) short s16x4;

typedef __attribute__((address_space(3))) unsigned int lds_u32;
typedef __attribute__((address_space(1))) const unsigned int glb_u32;

__device__ __forceinline__ void gl_lds16(const void* g, void* l) {
  __builtin_amdgcn_global_load_lds((glb_u32*)g, (lds_u32*)l, 16, 0, 0);
}

__device__ __forceinline__ unsigned short f2bf(float f) {
  union { float f; unsigned int u; } a; a.f = f;
  unsigned int u = a.u;
  unsigned int r = (u + 0x7FFFu + ((u >> 16) & 1u)) >> 16;
  return (unsigned short)r;
}

__device__ __forceinline__ float b2f(unsigned short h) {
  union { unsigned int u; float f; } a;
  a.u = ((unsigned int)h) << 16;
  return a.f;
}

// bijective chunked XCD swizzle (m204)
__device__ __forceinline__ int xcd_swz(int bid, int nwg) {
  int q = nwg >> 3, r = nwg & 7;
  int xcd = bid & 7, pos = bid >> 3;
  int base = (xcd < r) ? xcd * (q + 1) : r * (q + 1) + (xcd - r) * q;
  return base + pos;
}

// ---------------- fused router + fp32->bf16 conversion (x, gate_up_w only) ----------------
__global__ void convert_router(const float* __restrict__ x, unsigned short* __restrict__ xb, int n4x,
                               const float* __restrict__ guw, unsigned short* __restrict__ guwb, int n4g,
                               const float* __restrict__ rw, const float* __restrict__ rb, int T,
                               int* __restrict__ tokE, float* __restrict__ tokW) {
  int nr = T / 4;   // router blocks (4 waves = 4 tokens each)
  if ((int)blockIdx.x < nr) {
    int gwid = blockIdx.x * 4 + (threadIdx.x >> 6);
    int lane = threadIdx.x & 63;
    if (gwid >= T) return;
    const float* h = x + (size_t)gwid * EMB;
    float hreg[16];
    #pragma unroll
    for (int i = 0; i < 16; ++i) hreg[i] = h[lane + 64 * i];
    float sc[NEXP];
    #pragma unroll
    for (int e = 0; e < NEXP; ++e) {
      const float* w = rw + e * EMB;
      float s = 0.f;
      #pragma unroll
      for (int i = 0; i < 16; ++i) s += hreg[i] * w[lane + 64 * i];
      #pragma unroll
      for (int off = 32; off > 0; off >>= 1) s += __shfl_xor(s, off);
      sc[e] = s + rb[e];
    }
    if (lane == 0) {
      int e0 = 0; float v0 = sc[0];
      #pragma unroll
      for (int e = 1; e < NEXP; ++e) if (sc[e] > v0) { v0 = sc[e]; e0 = e; }
      int e1 = -1; float v1 = -3.0e38f;
      #pragma unroll
      for (int e = 0; e < NEXP; ++e) { if (e == e0) continue; if (sc[e] > v1) { v1 = sc[e]; e1 = e; } }
      float ex = __expf(v1 - v0);
      float w0 = 1.f / (1.f + ex);
      float w1 = ex / (1.f + ex);
      tokE[gwid * 2] = e0; tokE[gwid * 2 + 1] = e1;
      tokW[gwid * 2] = w0; tokW[gwid * 2 + 1] = w1;
    }
  } else {
    int tot = n4x + n4g;
    int base = (blockIdx.x - nr) * blockDim.x + threadIdx.x;
    int stride = (gridDim.x - nr) * blockDim.x;
    for (int i = base; i < tot; i += stride) {
      const float* src; unsigned short* dst; int k;
      if (i < n4x) { src = x; dst = xb; k = i; }
      else { src = guw; dst = guwb; k = i - n4x; }
      float4 v = ((const float4*)src)[k];
      s16x4 o;
      o[0] = (short)f2bf(v.x);
      o[1] = (short)f2bf(v.y);
      o[2] = (short)f2bf(v.z);
      o[3] = (short)f2bf(v.w);
      ((s16x4*)dst)[k] = o;
    }
  }
}

// ---------------- fused histogram + offsets + tile map + scatter (single block) ----------------
__global__ void meta_scatter(const int* __restrict__ tokE, int A,
                             int* __restrict__ tilemeta,
                             int* __restrict__ rows, int* __restrict__ apos) {
  __shared__ int hist[NEXP];
  __shared__ int offs[NEXP];
  __shared__ int fill[NEXP];
  int t = threadIdx.x;
  if (t < NEXP) { hist[t] = 0; fill[t] = 0; }
  __syncthreads();
  for (int i = t; i < A; i += blockDim.x) atomicAdd(&hist[tokE[i]], 1);
  __syncthreads();
  if (t == 0) {
    int off = 0, nt = 0;
    for (int e = 0; e < NEXP; ++e) {
      offs[e] = off;
      int c = hist[e];
      int ntile = (c + BM - 1) / BM;
      for (int k = 0; k < ntile; ++k) {
        tilemeta[1 + nt * 3 + 0] = e;
        tilemeta[1 + nt * 3 + 1] = off + k * BM;
        tilemeta[1 + nt * 3 + 2] = off + c;
        nt++;
      }
      off += c;
    }
    tilemeta[0] = nt;
  }
  __syncthreads();
  for (int i = t; i < A; i += blockDim.x) {
    int e = tokE[i];
    int p = offs[e] + atomicAdd(&fill[e], 1);
    rows[p] = i >> 1;
    apos[i] = p;
  }
}

// ---------------- grouped GEMM 1: gathered x @ gate_up_w[e]^T, fused SwiGLU ----------------
// R12-proven plain 2-phase loop, single-buffer 32KB LDS, 4 blocks/CU (ledger: 7 structural
// variants — dbuf, counted-vmcnt, 256^2-2ph, BK32 ring, BK32 dbuf, 256x128, 8-phase — ALL lose).
// + CONV_BLKS trailing converter-role blocks: dw fp32->bf16 (pure-BW, hides under compute, m114).
__global__ __launch_bounds__(256, 4) void gemm_gate_up(
    const unsigned short* __restrict__ xb,
    const unsigned short* __restrict__ gub,
    const float* __restrict__ gu_bias,
    const int* __restrict__ rows,
    const int* __restrict__ tilemeta,
    unsigned short* __restrict__ hact,
    const float* __restrict__ dw, unsigned short* __restrict__ dwb, int n4d) {
  __shared__ __align__(16) short As[BM * BK];
  __shared__ __align__(16) short Bs[BN * BK];
  if ((int)blockIdx.x >= GRID_GU) {
    // converter role: down_w fp32 -> bf16 (needed only by gemm_down)
    int base = ((int)blockIdx.x - GRID_GU) * blockDim.x + threadIdx.x;
    int stride = CONV_BLKS * blockDim.x;
    for (int i = base; i < n4d; i += stride) {
      float4 v = ((const float4*)dw)[i];
      s16x4 o;
      o[0] = (short)f2bf(v.x);
      o[1] = (short)f2bf(v.y);
      o[2] = (short)f2bf(v.z);
      o[3] = (short)f2bf(v.w);
      ((s16x4*)dwb)[i] = o;
    }
    return;
  }
  int wg = xcd_swz(blockIdx.x, GRID_GU);
  int tileid = wg >> 4;          // n = wg & 15 fast axis (A-tile reuse adjacency)
  int n0 = (wg & 15) * BN;
  int nt = tilemeta[0];
  if (tileid >= nt) return;
  int e    = tilemeta[1 + tileid * 3 + 0];
  int m0   = tilemeta[1 + tileid * 3 + 1];
  int mEnd = tilemeta[1 + tileid * 3 + 2];

  int t = threadIdx.x;
  int lane = t & 63;
  int wid = t >> 6;
  int wr = wid >> 1, wc = wid & 1;

  // staging: inst q covers rows wid*32+q*8..+8; lane l -> row +(l>>3), LDS chunk (l&7).
  // SOURCE pre-swizzle (rule #21): fetch global chunk (l&7) ^ (row&7).
  int srow = lane >> 3;
  int scol = (((lane & 7) ^ (srow & 7)) * 8);
  const unsigned short* ga[4];
  const unsigned short* gb[4];
  int dstoff[4];
  #pragma unroll
  for (int q = 0; q < 4; ++q) {
    int rt = wid * 32 + q * 8 + srow;
    int ai = m0 + rt; if (ai >= mEnd) ai = mEnd - 1;
    ga[q] = xb + (size_t)rows[ai] * EMB + scol;
    gb[q] = gub + ((size_t)e * N_GU + n0 + rt) * EMB + scol;
    dstoff[q] = (wid * 32 + q * 8) * BK;
  }

  int fr = lane & 15;
  int q8 = (lane >> 4) * 8;
  int rsw = (fr & 7) << 3;       // read-side swizzle (elem), row&7 = fr&7

  f32x4 acc[4][4];
  #pragma unroll
  for (int i = 0; i < 4; ++i)
    #pragma unroll
    for (int j = 0; j < 4; ++j) acc[i][j] = (f32x4){0.f, 0.f, 0.f, 0.f};

  for (int tk = 0; tk < KTILES; ++tk) {
    int k0 = tk * BK;
    __syncthreads();             // buffer free (previous compute done)
    #pragma unroll
    for (int q = 0; q < 4; ++q) {
      gl_lds16(ga[q] + k0, &As[dstoff[q]]);
      gl_lds16(gb[q] + k0, &Bs[dstoff[q]]);
    }
    __syncthreads();             // implicit vmcnt(0) drain: tile visible to all waves
    #pragma unroll
    for (int kk = 0; kk < BK; kk += 32) {
      s16x8 a[4], b[4];
      #pragma unroll
      for (int i = 0; i < 4; ++i)
        a[i] = *(const s16x8*)(&As[(wr * 64 + i * 16 + fr) * BK + ((kk + q8) ^ rsw)]);
      #pragma unroll
      for (int j = 0; j < 4; ++j)
        b[j] = *(const s16x8*)(&Bs[(wc * 64 + j * 16 + fr) * BK + ((kk + q8) ^ rsw)]);
      #pragma unroll
      for (int i = 0; i < 4; ++i)
        #pragma unroll
        for (int j = 0; j < 4; ++j)
          acc[i][j] = __builtin_amdgcn_mfma_f32_16x16x32_bf16(a[i], b[j], acc[i][j], 0, 0, 0);
    }
  }

  // epilogue: bias + SwiGLU (pair even/odd N via shfl_xor 1) -> bf16 hact
  const float* bias_e = gu_bias + (size_t)e * N_GU;
  int rbase = m0 + wr * 64 + ((lane >> 4) * 4);
  #pragma unroll
  for (int i = 0; i < 4; ++i) {
    #pragma unroll
    for (int j = 0; j < 4; ++j) {
      int n = n0 + wc * 64 + j * 16 + fr;
      float v[4], o[4];
      #pragma unroll
      for (int r = 0; r < 4; ++r) v[r] = acc[i][j][r] + bias_e[n];
      #pragma unroll
      for (int r = 0; r < 4; ++r) o[r] = __shfl_xor(v[r], 1);
      if ((lane & 1) == 0) {
        int outc = n >> 1;
        #pragma unroll
        for (int r = 0; r < 4; ++r) {
          int pos = rbase + i * 16 + r;
          if (pos < mEnd) {
            float g = v[r], u = o[r];
            float gc = fminf(fmaxf(g, -7.f), 7.f);
            float uc = fminf(fmaxf(u, -7.f), 7.f);
            float sig = 1.f / (1.f + __expf(-1.702f * g));
            float act = gc * sig * (uc + 1.f);
            hact[(size_t)pos * NH + outc] = f2bf(act);
          }
        }
      }
    }
  }
}

// ---------------- grouped GEMM 2: hact @ down_w[e]^T -> y (bf16) ----------------
__global__ __launch_bounds__(256, 4) void gemm_down(
    const unsigned short* __restrict__ hact,
    const unsigned short* __restrict__ dwb,
    const int* __restrict__ tilemeta,
    unsigned short* __restrict__ y) {
  __shared__ __align__(16) short As[BM * BK];
  __shared__ __align__(16) short Bs[BN * BK];
  int wg = xcd_swz(blockIdx.x, gridDim.x);
  int tileid = wg >> 3;          // n = wg & 7 fast axis
  int n0 = (wg & 7) * BN;
  int nt = tilemeta[0];
  if (tileid >= nt) return;
  int e    = tilemeta[1 + tileid * 3 + 0];
  int m0   = tilemeta[1 + tileid * 3 + 1];
  int mEnd = tilemeta[1 + tileid * 3 + 2];

  int t = threadIdx.x;
  int lane = t & 63;
  int wid = t >> 6;
  int wr = wid >> 1, wc = wid & 1;

  int srow = lane >> 3;
  int scol = (((lane & 7) ^ (srow & 7)) * 8);
  const unsigned short* ga[4];
  const unsigned short* gb[4];
  int dstoff[4];
  #pragma unroll
  for (int q = 0; q < 4; ++q) {
    int rt = wid * 32 + q * 8 + srow;
    int ai = m0 + rt; if (ai >= mEnd) ai = mEnd - 1;
    ga[q] = hact + (size_t)ai * NH + scol;
    gb[q] = dwb + ((size_t)e * EMB + n0 + rt) * NH + scol;
    dstoff[q] = (wid * 32 + q * 8) * BK;
  }

  int fr = lane & 15;
  int q8 = (lane >> 4) * 8;
  int rsw = (fr & 7) << 3;

  f32x4 acc[4][4];
  #pragma unroll
  for (int i = 0; i < 4; ++i)
    #pragma unroll
    for (int j = 0; j < 4; ++j) acc[i][j] = (f32x4){0.f, 0.f, 0.f, 0.f};

  for (int tk = 0; tk < KTILES; ++tk) {
    int k0 = tk * BK;
    __syncthreads();
    #pragma unroll
    for (int q = 0; q < 4; ++q) {
      gl_lds16(ga[q] + k0, &As[dstoff[q]]);
      gl_lds16(gb[q] + k0, &Bs[dstoff[q]]);
    }
    __syncthreads();
    #pragma unroll
    for (int kk = 0; kk < BK; kk += 32) {
      s16x8 a[4], b[4];
      #pragma unroll
      for (int i = 0; i < 4; ++i)
        a[i] = *(const s16x8*)(&As[(wr * 64 + i * 16 + fr) * BK + ((kk + q8) ^ rsw)]);
      #pragma unroll
      for (int j = 0; j < 4; ++j)
        b[j] = *(const s16x8*)(&Bs[(wc * 64 + j * 16 + fr) * BK + ((kk + q8) ^ rsw)]);
      #pragma unroll
      for (int i = 0; i < 4; ++i)
        #pragma unroll
        for (int j = 0; j < 4; ++j)
          acc[i][j] = __builtin_amdgcn_mfma_f32_16x16x32_bf16(a[i], b[j], acc[i][j], 0, 0, 0);
    }
  }

  int rbase = m0 + wr * 64 + ((lane >> 4) * 4);
  #pragma unroll
  for (int i = 0; i < 4; ++i) {
    #pragma unroll
    for (int j = 0; j < 4; ++j) {
      int n = n0 + wc * 64 + j * 16 + fr;
      #pragma unroll
      for (int r = 0; r < 4; ++r) {
        int pos = rbase + i * 16 + r;
        if (pos < mEnd) y[(size_t)pos * EMB + n] = f2bf(acc[i][j][r]);
      }
    }
  }
}

// ---------------- final combine (bf16 y) ----------------
__global__ void combine_out(const unsigned short* __restrict__ y, const float* __restrict__ down_b,
                            const int* __restrict__ tokE, const float* __restrict__ tokW,
                            const int* __restrict__ apos, float* __restrict__ out, int T) {
  int i = blockIdx.x * blockDim.x + threadIdx.x;
  int tot = T * (EMB / 4);
  if (i >= tot) return;
  int tok = i >> 8;
  int c = i & 255;
  int e0 = tokE[tok * 2], e1 = tokE[tok * 2 + 1];
  float w0 = tokW[tok * 2], w1 = tokW[tok * 2 + 1];
  int p0 = apos[tok * 2], p1 = apos[tok * 2 + 1];
  s16x4 v0 = ((const s16x4*)(y + (size_t)p0 * EMB))[c];
  s16x4 v1 = ((const s16x4*)(y + (size_t)p1 * EMB))[c];
  float4 b0 = ((const float4*)(down_b + (size_t)e0 * EMB))[c];
  float4 b1 = ((const float4*)(down_b + (size_t)e1 * EMB))[c];
  float4 o;
  o.x = w0 * (b2f((unsigned short)v0[0]) + b0.x) + w1 * (b2f((unsigned short)v1[0]) + b1.x);
  o.y = w0 * (b2f((unsigned short)v0[1]) + b0.y) + w1 * (b2f((unsigned short)v1[1]) + b1.y);
  o.z = w0 * (b2f((unsigned short)v0[2]) + b0.z) + w1 * (b2f((unsigned short)v1[2]) + b1.z);
  o.w = w0 * (b2f((unsigned short)v0[3]) + b0.w) + w1 * (b2f((unsigned short)v1[3]) + b1.w);
  ((float4*)out)[i] = o;
}

extern "C" void kernel_launch(void* const* d_in, const int* in_sizes, int n_in,
                              void* d_out, int out_size, void* d_ws, size_t ws_size,
                              hipStream_t stream) {
  const float* x   = (const float*)d_in[0];
  const float* rw  = (const float*)d_in[1];
  const float* rb  = (const float*)d_in[2];
  const float* guw = (const float*)d_in[3];
  const float* gub = (const float*)d_in[4];
  const float* dw  = (const float*)d_in[5];
  const float* db  = (const float*)d_in[6];
  float* out = (float*)d_out;

  int T = in_sizes[0] / EMB;   // 4096
  int A = T * TOPK;            // 8192

  char* ws = (char*)d_ws;
  size_t off = 0;
  auto alloc = [&](size_t bytes) -> void* {
    void* p = ws + off;
    off = (off + bytes + 255) & ~((size_t)255);
    return p;
  };
  unsigned short* xb   = (unsigned short*)alloc((size_t)T * EMB * 2);
  unsigned short* guwb = (unsigned short*)alloc((size_t)NEXP * N_GU * EMB * 2);
  unsigned short* dwb  = (unsigned short*)alloc((size_t)NEXP * EMB * NH * 2);
  unsigned short* hact = (unsigned short*)alloc((size_t)A * NH * 2);
  unsigned short* y    = (unsigned short*)alloc((size_t)A * EMB * 2);
  int*   tokE    = (int*)alloc((size_t)A * 4);
  float* tokW    = (float*)alloc((size_t)A * 4);
  int*   apos    = (int*)alloc((size_t)A * 4);
  int*   rowsArr = (int*)alloc((size_t)A * 4);
  int*   tilemeta= (int*)alloc((1 + MAXTILES * 3) * 4);

  int n4x = T * EMB / 4;
  int n4g = NEXP * N_GU * EMB / 4;
  int n4d = NEXP * EMB * NH / 4;
  convert_router<<<T / 4 + 2048, 256, 0, stream>>>(x, xb, n4x, guw, guwb, n4g,
                                                   rw, rb, T, tokE, tokW);

  meta_scatter<<<1, 1024, 0, stream>>>(tokE, A, tilemeta, rowsArr, apos);

  gemm_gate_up<<<GRID_GU + CONV_BLKS, 256, 0, stream>>>(xb, guwb, gub, rowsArr, tilemeta, hact,
                                                        dw, dwb, n4d);
  gemm_down<<<MAXTILES * (EMB / BN), 256, 0, stream>>>(hact, dwb, tilemeta, y);

  combine_out<<<(T * EMB / 4 + 255) / 256, 256, 0, stream>>>(y, db, tokE, tokW, apos, out, T);
}

// Round 16
// 135.601 us; speedup vs baseline: 1.2614x; 1.0045x over previous
//
#include <hip/hip_runtime.h>
#include <hip/hip_bf16.h>

#define EMB 1024
#define NEXP 8
#define NH 1024
#define N_GU 2048
#define TOPK 2

#define BM 64
#define BN 128
#define BK 64
#define KTILES 16      // 1024 / 64
#define MAXTILES 160   // sum ceil(c_e/64) <= 128+8
#define GRID_GU (MAXTILES * 16)
#define CONV_BLKS 256

typedef __attribute__((ext_vector_type(4))) float f32x4;
typedef __attribute__((ext_vector_type(8))) short s16x8;
typedef __attribute__((ext_vector_type(4))) short s16x4;

typedef __attribute__((address_space(3))) unsigned int lds_u32;
typedef __attribute__((address_space(1))) const unsigned int glb_u32;

__device__ __forceinline__ void gl_lds16(const void* g, void* l) {
  __builtin_amdgcn_global_load_lds((glb_u32*)g, (lds_u32*)l, 16, 0, 0);
}

__device__ __forceinline__ unsigned short f2bf(float f) {
  union { float f; unsigned int u; } a; a.f = f;
  unsigned int u = a.u;
  unsigned int r = (u + 0x7FFFu + ((u >> 16) & 1u)) >> 16;
  return (unsigned short)r;
}

__device__ __forceinline__ float b2f(unsigned short h) {
  union { unsigned int u; float f; } a;
  a.u = ((unsigned int)h) << 16;
  return a.f;
}

// bijective chunked XCD swizzle (m204)
__device__ __forceinline__ int xcd_swz(int bid, int nwg) {
  int q = nwg >> 3, r = nwg & 7;
  int xcd = bid & 7, pos = bid >> 3;
  int base = (xcd < r) ? xcd * (q + 1) : r * (q + 1) + (xcd - r) * q;
  return base + pos;
}

// ---------------- fused router + fp32->bf16 conversion (x, gate_up_w only) ----------------
__global__ void convert_router(const float* __restrict__ x, unsigned short* __restrict__ xb, int n4x,
                               const float* __restrict__ guw, unsigned short* __restrict__ guwb, int n4g,
                               const float* __restrict__ rw, const float* __restrict__ rb, int T,
                               int* __restrict__ tokE, float* __restrict__ tokW) {
  int nr = T / 4;   // router blocks (4 waves = 4 tokens each)
  if ((int)blockIdx.x < nr) {
    int gwid = blockIdx.x * 4 + (threadIdx.x >> 6);
    int lane = threadIdx.x & 63;
    if (gwid >= T) return;
    const float* h = x + (size_t)gwid * EMB;
    float hreg[16];
    #pragma unroll
    for (int i = 0; i < 16; ++i) hreg[i] = h[lane + 64 * i];
    float sc[NEXP];
    #pragma unroll
    for (int e = 0; e < NEXP; ++e) {
      const float* w = rw + e * EMB;
      float s = 0.f;
      #pragma unroll
      for (int i = 0; i < 16; ++i) s += hreg[i] * w[lane + 64 * i];
      #pragma unroll
      for (int off = 32; off > 0; off >>= 1) s += __shfl_xor(s, off);
      sc[e] = s + rb[e];
    }
    if (lane == 0) {
      int e0 = 0; float v0 = sc[0];
      #pragma unroll
      for (int e = 1; e < NEXP; ++e) if (sc[e] > v0) { v0 = sc[e]; e0 = e; }
      int e1 = -1; float v1 = -3.0e38f;
      #pragma unroll
      for (int e = 0; e < NEXP; ++e) { if (e == e0) continue; if (sc[e] > v1) { v1 = sc[e]; e1 = e; } }
      float ex = __expf(v1 - v0);
      float w0 = 1.f / (1.f + ex);
      float w1 = ex / (1.f + ex);
      tokE[gwid * 2] = e0; tokE[gwid * 2 + 1] = e1;
      tokW[gwid * 2] = w0; tokW[gwid * 2 + 1] = w1;
    }
  } else {
    int tot = n4x + n4g;
    int base = (blockIdx.x - nr) * blockDim.x + threadIdx.x;
    int stride = (gridDim.x - nr) * blockDim.x;
    for (int i = base; i < tot; i += stride) {
      const float* src; unsigned short* dst; int k;
      if (i < n4x) { src = x; dst = xb; k = i; }
      else { src = guw; dst = guwb; k = i - n4x; }
      float4 v = ((const float4*)src)[k];
      s16x4 o;
      o[0] = (short)f2bf(v.x);
      o[1] = (short)f2bf(v.y);
      o[2] = (short)f2bf(v.z);
      o[3] = (short)f2bf(v.w);
      ((s16x4*)dst)[k] = o;
    }
  }
}

// ---------------- fused histogram + offsets + tile map + scatter (single block) ----------------
__global__ void meta_scatter(const int* __restrict__ tokE, int A,
                             int* __restrict__ tilemeta,
                             int* __restrict__ rows, int* __restrict__ apos) {
  __shared__ int hist[NEXP];
  __shared__ int offs[NEXP];
  __shared__ int fill[NEXP];
  int t = threadIdx.x;
  if (t < NEXP) { hist[t] = 0; fill[t] = 0; }
  __syncthreads();
  for (int i = t; i < A; i += blockDim.x) atomicAdd(&hist[tokE[i]], 1);
  __syncthreads();
  if (t == 0) {
    int off = 0, nt = 0;
    for (int e = 0; e < NEXP; ++e) {
      offs[e] = off;
      int c = hist[e];
      int ntile = (c + BM - 1) / BM;
      for (int k = 0; k < ntile; ++k) {
        tilemeta[1 + nt * 3 + 0] = e;
        tilemeta[1 + nt * 3 + 1] = off + k * BM;
        tilemeta[1 + nt * 3 + 2] = off + c;
        nt++;
      }
      off += c;
    }
    tilemeta[0] = nt;
  }
  __syncthreads();
  for (int i = t; i < A; i += blockDim.x) {
    int e = tokE[i];
    int p = offs[e] + atomicAdd(&fill[e], 1);
    rows[p] = i >> 1;
    apos[i] = p;
  }
}

// ---------------- grouped GEMM 1 (64x128): gathered x @ gate_up_w[e]^T, fused SwiGLU ----------------
// BM=64 doubles working-block count (~2100) -> 5-6 blocks/CU resident vs 2.5 at BM=128:
// cross-block TLP is this structure's proven win mechanism (R6/R12 ledger, m114).
// 24KB LDS; same 2-phase loop + R4-verified swizzle. + CONV_BLKS trailing dw-converter blocks.
__global__ __launch_bounds__(256, 6) void gemm_gate_up(
    const unsigned short* __restrict__ xb,
    const unsigned short* __restrict__ gub,
    const float* __restrict__ gu_bias,
    const int* __restrict__ rows,
    const int* __restrict__ tilemeta,
    unsigned short* __restrict__ hact,
    const float* __restrict__ dw, unsigned short* __restrict__ dwb, int n4d) {
  __shared__ __align__(16) short As[BM * BK];   // 8 KB
  __shared__ __align__(16) short Bs[BN * BK];   // 16 KB
  if ((int)blockIdx.x >= GRID_GU) {
    int base = ((int)blockIdx.x - GRID_GU) * blockDim.x + threadIdx.x;
    int stride = CONV_BLKS * blockDim.x;
    for (int i = base; i < n4d; i += stride) {
      float4 v = ((const float4*)dw)[i];
      s16x4 o;
      o[0] = (short)f2bf(v.x);
      o[1] = (short)f2bf(v.y);
      o[2] = (short)f2bf(v.z);
      o[3] = (short)f2bf(v.w);
      ((s16x4*)dwb)[i] = o;
    }
    return;
  }
  int wg = xcd_swz(blockIdx.x, GRID_GU);
  int tileid = wg >> 4;          // n = wg & 15 fast axis (N_GU/128 = 16)
  int n0 = (wg & 15) * BN;
  int nt = tilemeta[0];
  if (tileid >= nt) return;
  int e    = tilemeta[1 + tileid * 3 + 0];
  int m0   = tilemeta[1 + tileid * 3 + 1];
  int mEnd = tilemeta[1 + tileid * 3 + 2];

  int t = threadIdx.x;
  int lane = t & 63;
  int wid = t >> 6;
  int wr = wid >> 1, wc = wid & 1;   // wave owns 32x64: rows wr*32, cols wc*64

  // staging: round q -> 8 rows at q*32 + wid*8 (A: q<2) / q*32+wid*8 (B: q<4);
  // lane l -> row +(l>>3), LDS chunk (l&7). SOURCE pre-swizzle: chunk (l&7)^(row&7).
  int srow = lane >> 3;
  int scol = (((lane & 7) ^ (srow & 7)) * 8);
  const unsigned short* ga[2];
  const unsigned short* gb[4];
  int dstA[2], dstB[4];
  #pragma unroll
  for (int q = 0; q < 2; ++q) {
    int rt = q * 32 + wid * 8 + srow;
    int ai = m0 + rt; if (ai >= mEnd) ai = mEnd - 1;
    ga[q] = xb + (size_t)rows[ai] * EMB + scol;
    dstA[q] = (q * 32 + wid * 8) * BK;
  }
  #pragma unroll
  for (int q = 0; q < 4; ++q) {
    int rt = q * 32 + wid * 8 + srow;
    gb[q] = gub + ((size_t)e * N_GU + n0 + rt) * EMB + scol;
    dstB[q] = (q * 32 + wid * 8) * BK;
  }

  int fr = lane & 15;
  int q8 = (lane >> 4) * 8;
  int rsw = (fr & 7) << 3;       // read-side swizzle (elem), row&7 = fr&7

  f32x4 acc[2][4];
  #pragma unroll
  for (int i = 0; i < 2; ++i)
    #pragma unroll
    for (int j = 0; j < 4; ++j) acc[i][j] = (f32x4){0.f, 0.f, 0.f, 0.f};

  for (int tk = 0; tk < KTILES; ++tk) {
    int k0 = tk * BK;
    __syncthreads();             // buffer free
    #pragma unroll
    for (int q = 0; q < 2; ++q) gl_lds16(ga[q] + k0, &As[dstA[q]]);
    #pragma unroll
    for (int q = 0; q < 4; ++q) gl_lds16(gb[q] + k0, &Bs[dstB[q]]);
    __syncthreads();             // implicit vmcnt(0) drain: tile visible
    #pragma unroll
    for (int kk = 0; kk < BK; kk += 32) {
      s16x8 a[2], b[4];
      #pragma unroll
      for (int i = 0; i < 2; ++i)
        a[i] = *(const s16x8*)(&As[(wr * 32 + i * 16 + fr) * BK + ((kk + q8) ^ rsw)]);
      #pragma unroll
      for (int j = 0; j < 4; ++j)
        b[j] = *(const s16x8*)(&Bs[(wc * 64 + j * 16 + fr) * BK + ((kk + q8) ^ rsw)]);
      #pragma unroll
      for (int i = 0; i < 2; ++i)
        #pragma unroll
        for (int j = 0; j < 4; ++j)
          acc[i][j] = __builtin_amdgcn_mfma_f32_16x16x32_bf16(a[i], b[j], acc[i][j], 0, 0, 0);
    }
  }

  // epilogue: bias + SwiGLU (pair even/odd N via shfl_xor 1) -> bf16 hact
  const float* bias_e = gu_bias + (size_t)e * N_GU;
  int rbase = m0 + wr * 32 + ((lane >> 4) * 4);
  #pragma unroll
  for (int i = 0; i < 2; ++i) {
    #pragma unroll
    for (int j = 0; j < 4; ++j) {
      int n = n0 + wc * 64 + j * 16 + fr;
      float v[4], o[4];
      #pragma unroll
      for (int r = 0; r < 4; ++r) v[r] = acc[i][j][r] + bias_e[n];
      #pragma unroll
      for (int r = 0; r < 4; ++r) o[r] = __shfl_xor(v[r], 1);
      if ((lane & 1) == 0) {
        int outc = n >> 1;
        #pragma unroll
        for (int r = 0; r < 4; ++r) {
          int pos = rbase + i * 16 + r;
          if (pos < mEnd) {
            float g = v[r], u = o[r];
            float gc = fminf(fmaxf(g, -7.f), 7.f);
            float uc = fminf(fmaxf(u, -7.f), 7.f);
            float sig = 1.f / (1.f + __expf(-1.702f * g));
            float act = gc * sig * (uc + 1.f);
            hact[(size_t)pos * NH + outc] = f2bf(act);
          }
        }
      }
    }
  }
}

// ---------------- grouped GEMM 2 (64x128): hact @ down_w[e]^T -> y (bf16) ----------------
__global__ __launch_bounds__(256, 6) void gemm_down(
    const unsigned short* __restrict__ hact,
    const unsigned short* __restrict__ dwb,
    const int* __restrict__ tilemeta,
    unsigned short* __restrict__ y) {
  __shared__ __align__(16) short As[BM * BK];
  __shared__ __align__(16) short Bs[BN * BK];
  int wg = xcd_swz(blockIdx.x, gridDim.x);
  int tileid = wg >> 3;          // n = wg & 7 fast axis (EMB/128 = 8)
  int n0 = (wg & 7) * BN;
  int nt = tilemeta[0];
  if (tileid >= nt) return;
  int e    = tilemeta[1 + tileid * 3 + 0];
  int m0   = tilemeta[1 + tileid * 3 + 1];
  int mEnd = tilemeta[1 + tileid * 3 + 2];

  int t = threadIdx.x;
  int lane = t & 63;
  int wid = t >> 6;
  int wr = wid >> 1, wc = wid & 1;

  int srow = lane >> 3;
  int scol = (((lane & 7) ^ (srow & 7)) * 8);
  const unsigned short* ga[2];
  const unsigned short* gb[4];
  int dstA[2], dstB[4];
  #pragma unroll
  for (int q = 0; q < 2; ++q) {
    int rt = q * 32 + wid * 8 + srow;
    int ai = m0 + rt; if (ai >= mEnd) ai = mEnd - 1;
    ga[q] = hact + (size_t)ai * NH + scol;
    dstA[q] = (q * 32 + wid * 8) * BK;
  }
  #pragma unroll
  for (int q = 0; q < 4; ++q) {
    int rt = q * 32 + wid * 8 + srow;
    gb[q] = dwb + ((size_t)e * EMB + n0 + rt) * NH + scol;
    dstB[q] = (q * 32 + wid * 8) * BK;
  }

  int fr = lane & 15;
  int q8 = (lane >> 4) * 8;
  int rsw = (fr & 7) << 3;

  f32x4 acc[2][4];
  #pragma unroll
  for (int i = 0; i < 2; ++i)
    #pragma unroll
    for (int j = 0; j < 4; ++j) acc[i][j] = (f32x4){0.f, 0.f, 0.f, 0.f};

  for (int tk = 0; tk < KTILES; ++tk) {
    int k0 = tk * BK;
    __syncthreads();
    #pragma unroll
    for (int q = 0; q < 2; ++q) gl_lds16(ga[q] + k0, &As[dstA[q]]);
    #pragma unroll
    for (int q = 0; q < 4; ++q) gl_lds16(gb[q] + k0, &Bs[dstB[q]]);
    __syncthreads();
    #pragma unroll
    for (int kk = 0; kk < BK; kk += 32) {
      s16x8 a[2], b[4];
      #pragma unroll
      for (int i = 0; i < 2; ++i)
        a[i] = *(const s16x8*)(&As[(wr * 32 + i * 16 + fr) * BK + ((kk + q8) ^ rsw)]);
      #pragma unroll
      for (int j = 0; j < 4; ++j)
        b[j] = *(const s16x8*)(&Bs[(wc * 64 + j * 16 + fr) * BK + ((kk + q8) ^ rsw)]);
      #pragma unroll
      for (int i = 0; i < 2; ++i)
        #pragma unroll
        for (int j = 0; j < 4; ++j)
          acc[i][j] = __builtin_amdgcn_mfma_f32_16x16x32_bf16(a[i], b[j], acc[i][j], 0, 0, 0);
    }
  }

  int rbase = m0 + wr * 32 + ((lane >> 4) * 4);
  #pragma unroll
  for (int i = 0; i < 2; ++i) {
    #pragma unroll
    for (int j = 0; j < 4; ++j) {
      int n = n0 + wc * 64 + j * 16 + fr;
      #pragma unroll
      for (int r = 0; r < 4; ++r) {
        int pos = rbase + i * 16 + r;
        if (pos < mEnd) y[(size_t)pos * EMB + n] = f2bf(acc[i][j][r]);
      }
    }
  }
}

// ---------------- final combine (bf16 y) ----------------
__global__ void combine_out(const unsigned short* __restrict__ y, const float* __restrict__ down_b,
                            const int* __restrict__ tokE, const float* __restrict__ tokW,
                            const int* __restrict__ apos, float* __restrict__ out, int T) {
  int i = blockIdx.x * blockDim.x + threadIdx.x;
  int tot = T * (EMB / 4);
  if (i >= tot) return;
  int tok = i >> 8;
  int c = i & 255;
  int e0 = tokE[tok * 2], e1 = tokE[tok * 2 + 1];
  float w0 = tokW[tok * 2], w1 = tokW[tok * 2 + 1];
  int p0 = apos[tok * 2], p1 = apos[tok * 2 + 1];
  s16x4 v0 = ((const s16x4*)(y + (size_t)p0 * EMB))[c];
  s16x4 v1 = ((const s16x4*)(y + (size_t)p1 * EMB))[c];
  float4 b0 = ((const float4*)(down_b + (size_t)e0 * EMB))[c];
  float4 b1 = ((const float4*)(down_b + (size_t)e1 * EMB))[c];
  float4 o;
  o.x = w0 * (b2f((unsigned short)v0[0]) + b0.x) + w1 * (b2f((unsigned short)v1[0]) + b1.x);
  o.y = w0 * (b2f((unsigned short)v0[1]) + b0.y) + w1 * (b2f((unsigned short)v1[1]) + b1.y);
  o.z = w0 * (b2f((unsigned short)v0[2]) + b0.z) + w1 * (b2f((unsigned short)v1[2]) + b1.z);
  o.w = w0 * (b2f((unsigned short)v0[3]) + b0.w) + w1 * (b2f((unsigned short)v1[3]) + b1.w);
  ((float4*)out)[i] = o;
}

extern "C" void kernel_launch(void* const* d_in, const int* in_sizes, int n_in,
                              void* d_out, int out_size, void* d_ws, size_t ws_size,
                              hipStream_t stream) {
  const float* x   = (const float*)d_in[0];
  const float* rw  = (const float*)d_in[1];
  const float* rb  = (const float*)d_in[2];
  const float* guw = (const float*)d_in[3];
  const float* gub = (const float*)d_in[4];
  const float* dw  = (const float*)d_in[5];
  const float* db  = (const float*)d_in[6];
  float* out = (float*)d_out;

  int T = in_sizes[0] / EMB;   // 4096
  int A = T * TOPK;            // 8192

  char* ws = (char*)d_ws;
  size_t off = 0;
  auto alloc = [&](size_t bytes) -> void* {
    void* p = ws + off;
    off = (off + bytes + 255) & ~((size_t)255);
    return p;
  };
  unsigned short* xb   = (unsigned short*)alloc((size_t)T * EMB * 2);
  unsigned short* guwb = (unsigned short*)alloc((size_t)NEXP * N_GU * EMB * 2);
  unsigned short* dwb  = (unsigned short*)alloc((size_t)NEXP * EMB * NH * 2);
  unsigned short* hact = (unsigned short*)alloc((size_t)A * NH * 2);
  unsigned short* y    = (unsigned short*)alloc((size_t)A * EMB * 2);
  int*   tokE    = (int*)alloc((size_t)A * 4);
  float* tokW    = (float*)alloc((size_t)A * 4);
  int*   apos    = (int*)alloc((size_t)A * 4);
  int*   rowsArr = (int*)alloc((size_t)A * 4);
  int*   tilemeta= (int*)alloc((1 + MAXTILES * 3) * 4);

  int n4x = T * EMB / 4;
  int n4g = NEXP * N_GU * EMB / 4;
  int n4d = NEXP * EMB * NH / 4;
  convert_router<<<T / 4 + 2048, 256, 0, stream>>>(x, xb, n4x, guw, guwb, n4g,
                                                   rw, rb, T, tokE, tokW);

  meta_scatter<<<1, 1024, 0, stream>>>(tokE, A, tilemeta, rowsArr, apos);

  gemm_gate_up<<<GRID_GU + CONV_BLKS, 256, 0, stream>>>(xb, guwb, gub, rowsArr, tilemeta, hact,
                                                        dw, dwb, n4d);
  gemm_down<<<MAXTILES * (EMB / BN), 256, 0, stream>>>(hact, dwb, tilemeta, y);

  combine_out<<<(T * EMB / 4 + 255) / 256, 256, 0, stream>>>(y, db, tokE, tokW, apos, out, T);
}

// Round 17
// 133.376 us; speedup vs baseline: 1.2824x; 1.0167x over previous
//
#include <hip/hip_runtime.h>
#include <hip/hip_bf16.h>

#define EMB 1024
#define NEXP 8
#define NH 1024
#define N_GU 2048
#define TOPK 2

#define BK 64
#define KTILES 16      // 1024 / 64
#define BN 128

// gate_up: BM=128 (measured best at its grid size)
#define BMG 128
#define MAXTG 72
#define GRID_GU (MAXTG * 16)
#define CONV_BLKS 256

// down: BM=64 (measured best at its grid size)
#define BMD 64
#define MAXTD 160
#define GRID_DN (MAXTD * 8)

typedef __attribute__((ext_vector_type(4))) float f32x4;
typedef __attribute__((ext_vector_type(8))) short s16x8;
typedef __attribute__((ext_vector_type(4))) short s16x4;

typedef __attribute__((address_space(3))) unsigned int lds_u32;
typedef __attribute__((address_space(1))) const unsigned int glb_u32;

__device__ __forceinline__ void gl_lds16(const void* g, void* l) {
  __builtin_amdgcn_global_load_lds((glb_u32*)g, (lds_u32*)l, 16, 0, 0);
}

__device__ __forceinline__ unsigned short f2bf(float f) {
  union { float f; unsigned int u; } a; a.f = f;
  unsigned int u = a.u;
  unsigned int r = (u + 0x7FFFu + ((u >> 16) & 1u)) >> 16;
  return (unsigned short)r;
}

__device__ __forceinline__ float b2f(unsigned short h) {
  union { unsigned int u; float f; } a;
  a.u = ((unsigned int)h) << 16;
  return a.f;
}

// bijective chunked XCD swizzle (m204)
__device__ __forceinline__ int xcd_swz(int bid, int nwg) {
  int q = nwg >> 3, r = nwg & 7;
  int xcd = bid & 7, pos = bid >> 3;
  int base = (xcd < r) ? xcd * (q + 1) : r * (q + 1) + (xcd - r) * q;
  return base + pos;
}

// ---------------- dispatch 1: router + x fp32->bf16 ----------------
__global__ void router_convx(const float* __restrict__ x, unsigned short* __restrict__ xb, int n4x,
                             const float* __restrict__ rw, const float* __restrict__ rb, int T,
                             int* __restrict__ tokE, float* __restrict__ tokW) {
  int nr = T / 4;
  if ((int)blockIdx.x < nr) {
    int gwid = blockIdx.x * 4 + (threadIdx.x >> 6);
    int lane = threadIdx.x & 63;
    if (gwid >= T) return;
    const float* h = x + (size_t)gwid * EMB;
    float hreg[16];
    #pragma unroll
    for (int i = 0; i < 16; ++i) hreg[i] = h[lane + 64 * i];
    float sc[NEXP];
    #pragma unroll
    for (int e = 0; e < NEXP; ++e) {
      const float* w = rw + e * EMB;
      float s = 0.f;
      #pragma unroll
      for (int i = 0; i < 16; ++i) s += hreg[i] * w[lane + 64 * i];
      #pragma unroll
      for (int off = 32; off > 0; off >>= 1) s += __shfl_xor(s, off);
      sc[e] = s + rb[e];
    }
    if (lane == 0) {
      int e0 = 0; float v0 = sc[0];
      #pragma unroll
      for (int e = 1; e < NEXP; ++e) if (sc[e] > v0) { v0 = sc[e]; e0 = e; }
      int e1 = -1; float v1 = -3.0e38f;
      #pragma unroll
      for (int e = 0; e < NEXP; ++e) { if (e == e0) continue; if (sc[e] > v1) { v1 = sc[e]; e1 = e; } }
      float ex = __expf(v1 - v0);
      float w0 = 1.f / (1.f + ex);
      float w1 = ex / (1.f + ex);
      tokE[gwid * 2] = e0; tokE[gwid * 2 + 1] = e1;
      tokW[gwid * 2] = w0; tokW[gwid * 2 + 1] = w1;
    }
  } else {
    int base = (blockIdx.x - nr) * blockDim.x + threadIdx.x;
    int stride = (gridDim.x - nr) * blockDim.x;
    for (int i = base; i < n4x; i += stride) {
      float4 v = ((const float4*)x)[i];
      s16x4 o;
      o[0] = (short)f2bf(v.x);
      o[1] = (short)f2bf(v.y);
      o[2] = (short)f2bf(v.z);
      o[3] = (short)f2bf(v.w);
      ((s16x4*)xb)[i] = o;
    }
  }
}

// ---------------- dispatch 2: meta/scatter (block 0) || guw fp32->bf16 (rest) ----------------
__global__ void meta_convw(const int* __restrict__ tokE, int A,
                           int* __restrict__ tmG, int* __restrict__ tmD,
                           int* __restrict__ rows, int* __restrict__ apos,
                           const float* __restrict__ guw, unsigned short* __restrict__ guwb, int n4g) {
  if (blockIdx.x > 0) {
    int base = (blockIdx.x - 1) * blockDim.x + threadIdx.x;
    int stride = (gridDim.x - 1) * blockDim.x;
    for (int i = base; i < n4g; i += stride) {
      float4 v = ((const float4*)guw)[i];
      s16x4 o;
      o[0] = (short)f2bf(v.x);
      o[1] = (short)f2bf(v.y);
      o[2] = (short)f2bf(v.z);
      o[3] = (short)f2bf(v.w);
      ((s16x4*)guwb)[i] = o;
    }
    return;
  }
  __shared__ int hist[NEXP];
  __shared__ int offs[NEXP];
  __shared__ int fill[NEXP];
  int t = threadIdx.x;
  if (t < NEXP) { hist[t] = 0; fill[t] = 0; }
  __syncthreads();
  for (int i = t; i < A; i += blockDim.x) atomicAdd(&hist[tokE[i]], 1);
  __syncthreads();
  if (t == 0) {
    int off = 0, ntg = 0, ntd = 0;
    for (int e = 0; e < NEXP; ++e) {
      offs[e] = off;
      int c = hist[e];
      int ng = (c + BMG - 1) / BMG;
      for (int k = 0; k < ng; ++k) {
        tmG[1 + ntg * 3 + 0] = e;
        tmG[1 + ntg * 3 + 1] = off + k * BMG;
        tmG[1 + ntg * 3 + 2] = off + c;
        ntg++;
      }
      int nd = (c + BMD - 1) / BMD;
      for (int k = 0; k < nd; ++k) {
        tmD[1 + ntd * 3 + 0] = e;
        tmD[1 + ntd * 3 + 1] = off + k * BMD;
        tmD[1 + ntd * 3 + 2] = off + c;
        ntd++;
      }
      off += c;
    }
    tmG[0] = ntg;
    tmD[0] = ntd;
  }
  __syncthreads();
  for (int i = t; i < A; i += blockDim.x) {
    int e = tokE[i];
    int p = offs[e] + atomicAdd(&fill[e], 1);
    rows[p] = i >> 1;
    apos[i] = p;
  }
}

// ---------------- grouped GEMM 1 (128x128): gathered x @ gate_up_w[e]^T, fused SwiGLU ----------------
// R12/R15-proven plain 2-phase loop, single-buffer 32KB LDS, 4 blocks/CU.
// + CONV_BLKS trailing converter-role blocks: dw fp32->bf16 (hides under GEMM, m114).
__global__ __launch_bounds__(256, 4) void gemm_gate_up(
    const unsigned short* __restrict__ xb,
    const unsigned short* __restrict__ gub,
    const float* __restrict__ gu_bias,
    const int* __restrict__ rows,
    const int* __restrict__ tilemeta,
    unsigned short* __restrict__ hact,
    const float* __restrict__ dw, unsigned short* __restrict__ dwb, int n4d) {
  __shared__ __align__(16) short As[BMG * BK];
  __shared__ __align__(16) short Bs[BN * BK];
  if ((int)blockIdx.x >= GRID_GU) {
    int base = ((int)blockIdx.x - GRID_GU) * blockDim.x + threadIdx.x;
    int stride = CONV_BLKS * blockDim.x;
    for (int i = base; i < n4d; i += stride) {
      float4 v = ((const float4*)dw)[i];
      s16x4 o;
      o[0] = (short)f2bf(v.x);
      o[1] = (short)f2bf(v.y);
      o[2] = (short)f2bf(v.z);
      o[3] = (short)f2bf(v.w);
      ((s16x4*)dwb)[i] = o;
    }
    return;
  }
  int wg = xcd_swz(blockIdx.x, GRID_GU);
  int tileid = wg >> 4;          // n = wg & 15 fast axis
  int n0 = (wg & 15) * BN;
  int nt = tilemeta[0];
  if (tileid >= nt) return;
  int e    = tilemeta[1 + tileid * 3 + 0];
  int m0   = tilemeta[1 + tileid * 3 + 1];
  int mEnd = tilemeta[1 + tileid * 3 + 2];

  int t = threadIdx.x;
  int lane = t & 63;
  int wid = t >> 6;
  int wr = wid >> 1, wc = wid & 1;

  int srow = lane >> 3;
  int scol = (((lane & 7) ^ (srow & 7)) * 8);
  const unsigned short* ga[4];
  const unsigned short* gb[4];
  int dstoff[4];
  #pragma unroll
  for (int q = 0; q < 4; ++q) {
    int rt = wid * 32 + q * 8 + srow;
    int ai = m0 + rt; if (ai >= mEnd) ai = mEnd - 1;
    ga[q] = xb + (size_t)rows[ai] * EMB + scol;
    gb[q] = gub + ((size_t)e * N_GU + n0 + rt) * EMB + scol;
    dstoff[q] = (wid * 32 + q * 8) * BK;
  }

  int fr = lane & 15;
  int q8 = (lane >> 4) * 8;
  int rsw = (fr & 7) << 3;

  f32x4 acc[4][4];
  #pragma unroll
  for (int i = 0; i < 4; ++i)
    #pragma unroll
    for (int j = 0; j < 4; ++j) acc[i][j] = (f32x4){0.f, 0.f, 0.f, 0.f};

  for (int tk = 0; tk < KTILES; ++tk) {
    int k0 = tk * BK;
    __syncthreads();
    #pragma unroll
    for (int q = 0; q < 4; ++q) {
      gl_lds16(ga[q] + k0, &As[dstoff[q]]);
      gl_lds16(gb[q] + k0, &Bs[dstoff[q]]);
    }
    __syncthreads();
    #pragma unroll
    for (int kk = 0; kk < BK; kk += 32) {
      s16x8 a[4], b[4];
      #pragma unroll
      for (int i = 0; i < 4; ++i)
        a[i] = *(const s16x8*)(&As[(wr * 64 + i * 16 + fr) * BK + ((kk + q8) ^ rsw)]);
      #pragma unroll
      for (int j = 0; j < 4; ++j)
        b[j] = *(const s16x8*)(&Bs[(wc * 64 + j * 16 + fr) * BK + ((kk + q8) ^ rsw)]);
      #pragma unroll
      for (int i = 0; i < 4; ++i)
        #pragma unroll
        for (int j = 0; j < 4; ++j)
          acc[i][j] = __builtin_amdgcn_mfma_f32_16x16x32_bf16(a[i], b[j], acc[i][j], 0, 0, 0);
    }
  }

  const float* bias_e = gu_bias + (size_t)e * N_GU;
  int rbase = m0 + wr * 64 + ((lane >> 4) * 4);
  #pragma unroll
  for (int i = 0; i < 4; ++i) {
    #pragma unroll
    for (int j = 0; j < 4; ++j) {
      int n = n0 + wc * 64 + j * 16 + fr;
      float v[4], o[4];
      #pragma unroll
      for (int r = 0; r < 4; ++r) v[r] = acc[i][j][r] + bias_e[n];
      #pragma unroll
      for (int r = 0; r < 4; ++r) o[r] = __shfl_xor(v[r], 1);
      if ((lane & 1) == 0) {
        int outc = n >> 1;
        #pragma unroll
        for (int r = 0; r < 4; ++r) {
          int pos = rbase + i * 16 + r;
          if (pos < mEnd) {
            float g = v[r], u = o[r];
            float gc = fminf(fmaxf(g, -7.f), 7.f);
            float uc = fminf(fmaxf(u, -7.f), 7.f);
            float sig = 1.f / (1.f + __expf(-1.702f * g));
            float act = gc * sig * (uc + 1.f);
            hact[(size_t)pos * NH + outc] = f2bf(act);
          }
        }
      }
    }
  }
}

// ---------------- grouped GEMM 2 (64x128): hact @ down_w[e]^T -> y (bf16) ----------------
__global__ __launch_bounds__(256, 6) void gemm_down(
    const unsigned short* __restrict__ hact,
    const unsigned short* __restrict__ dwb,
    const int* __restrict__ tilemeta,
    unsigned short* __restrict__ y) {
  __shared__ __align__(16) short As[BMD * BK];
  __shared__ __align__(16) short Bs[BN * BK];
  int wg = xcd_swz(blockIdx.x, gridDim.x);
  int tileid = wg >> 3;          // n = wg & 7 fast axis
  int n0 = (wg & 7) * BN;
  int nt = tilemeta[0];
  if (tileid >= nt) return;
  int e    = tilemeta[1 + tileid * 3 + 0];
  int m0   = tilemeta[1 + tileid * 3 + 1];
  int mEnd = tilemeta[1 + tileid * 3 + 2];

  int t = threadIdx.x;
  int lane = t & 63;
  int wid = t >> 6;
  int wr = wid >> 1, wc = wid & 1;   // wave owns 32x64

  int srow = lane >> 3;
  int scol = (((lane & 7) ^ (srow & 7)) * 8);
  const unsigned short* ga[2];
  const unsigned short* gb[4];
  int dstA[2], dstB[4];
  #pragma unroll
  for (int q = 0; q < 2; ++q) {
    int rt = q * 32 + wid * 8 + srow;
    int ai = m0 + rt; if (ai >= mEnd) ai = mEnd - 1;
    ga[q] = hact + (size_t)ai * NH + scol;
    dstA[q] = (q * 32 + wid * 8) * BK;
  }
  #pragma unroll
  for (int q = 0; q < 4; ++q) {
    int rt = q * 32 + wid * 8 + srow;
    gb[q] = dwb + ((size_t)e * EMB + n0 + rt) * NH + scol;
    dstB[q] = (q * 32 + wid * 8) * BK;
  }

  int fr = lane & 15;
  int q8 = (lane >> 4) * 8;
  int rsw = (fr & 7) << 3;

  f32x4 acc[2][4];
  #pragma unroll
  for (int i = 0; i < 2; ++i)
    #pragma unroll
    for (int j = 0; j < 4; ++j) acc[i][j] = (f32x4){0.f, 0.f, 0.f, 0.f};

  for (int tk = 0; tk < KTILES; ++tk) {
    int k0 = tk * BK;
    __syncthreads();
    #pragma unroll
    for (int q = 0; q < 2; ++q) gl_lds16(ga[q] + k0, &As[dstA[q]]);
    #pragma unroll
    for (int q = 0; q < 4; ++q) gl_lds16(gb[q] + k0, &Bs[dstB[q]]);
    __syncthreads();
    #pragma unroll
    for (int kk = 0; kk < BK; kk += 32) {
      s16x8 a[2], b[4];
      #pragma unroll
      for (int i = 0; i < 2; ++i)
        a[i] = *(const s16x8*)(&As[(wr * 32 + i * 16 + fr) * BK + ((kk + q8) ^ rsw)]);
      #pragma unroll
      for (int j = 0; j < 4; ++j)
        b[j] = *(const s16x8*)(&Bs[(wc * 64 + j * 16 + fr) * BK + ((kk + q8) ^ rsw)]);
      #pragma unroll
      for (int i = 0; i < 2; ++i)
        #pragma unroll
        for (int j = 0; j < 4; ++j)
          acc[i][j] = __builtin_amdgcn_mfma_f32_16x16x32_bf16(a[i], b[j], acc[i][j], 0, 0, 0);
    }
  }

  int rbase = m0 + wr * 32 + ((lane >> 4) * 4);
  #pragma unroll
  for (int i = 0; i < 2; ++i) {
    #pragma unroll
    for (int j = 0; j < 4; ++j) {
      int n = n0 + wc * 64 + j * 16 + fr;
      #pragma unroll
      for (int r = 0; r < 4; ++r) {
        int pos = rbase + i * 16 + r;
        if (pos < mEnd) y[(size_t)pos * EMB + n] = f2bf(acc[i][j][r]);
      }
    }
  }
}

// ---------------- final combine (bf16 y) ----------------
__global__ void combine_out(const unsigned short* __restrict__ y, const float* __restrict__ down_b,
                            const int* __restrict__ tokE, const float* __restrict__ tokW,
                            const int* __restrict__ apos, float* __restrict__ out, int T) {
  int i = blockIdx.x * blockDim.x + threadIdx.x;
  int tot = T * (EMB / 4);
  if (i >= tot) return;
  int tok = i >> 8;
  int c = i & 255;
  int e0 = tokE[tok * 2], e1 = tokE[tok * 2 + 1];
  float w0 = tokW[tok * 2], w1 = tokW[tok * 2 + 1];
  int p0 = apos[tok * 2], p1 = apos[tok * 2 + 1];
  s16x4 v0 = ((const s16x4*)(y + (size_t)p0 * EMB))[c];
  s16x4 v1 = ((const s16x4*)(y + (size_t)p1 * EMB))[c];
  float4 b0 = ((const float4*)(down_b + (size_t)e0 * EMB))[c];
  float4 b1 = ((const float4*)(down_b + (size_t)e1 * EMB))[c];
  float4 o;
  o.x = w0 * (b2f((unsigned short)v0[0]) + b0.x) + w1 * (b2f((unsigned short)v1[0]) + b1.x);
  o.y = w0 * (b2f((unsigned short)v0[1]) + b0.y) + w1 * (b2f((unsigned short)v1[1]) + b1.y);
  o.z = w0 * (b2f((unsigned short)v0[2]) + b0.z) + w1 * (b2f((unsigned short)v1[2]) + b1.z);
  o.w = w0 * (b2f((unsigned short)v0[3]) + b0.w) + w1 * (b2f((unsigned short)v1[3]) + b1.w);
  ((float4*)out)[i] = o;
}

extern "C" void kernel_launch(void* const* d_in, const int* in_sizes, int n_in,
                              void* d_out, int out_size, void* d_ws, size_t ws_size,
                              hipStream_t stream) {
  const float* x   = (const float*)d_in[0];
  const float* rw  = (const float*)d_in[1];
  const float* rb  = (const float*)d_in[2];
  const float* guw = (const float*)d_in[3];
  const float* gub = (const float*)d_in[4];
  const float* dw  = (const float*)d_in[5];
  const float* db  = (const float*)d_in[6];
  float* out = (float*)d_out;

  int T = in_sizes[0] / EMB;   // 4096
  int A = T * TOPK;            // 8192

  char* ws = (char*)d_ws;
  size_t off = 0;
  auto alloc = [&](size_t bytes) -> void* {
    void* p = ws + off;
    off = (off + bytes + 255) & ~((size_t)255);
    return p;
  };
  unsigned short* xb   = (unsigned short*)alloc((size_t)T * EMB * 2);
  unsigned short* guwb = (unsigned short*)alloc((size_t)NEXP * N_GU * EMB * 2);
  unsigned short* dwb  = (unsigned short*)alloc((size_t)NEXP * EMB * NH * 2);
  unsigned short* hact = (unsigned short*)alloc((size_t)A * NH * 2);
  unsigned short* y    = (unsigned short*)alloc((size_t)A * EMB * 2);
  int*   tokE    = (int*)alloc((size_t)A * 4);
  float* tokW    = (float*)alloc((size_t)A * 4);
  int*   apos    = (int*)alloc((size_t)A * 4);
  int*   rowsArr = (int*)alloc((size_t)A * 4);
  int*   tmG     = (int*)alloc((1 + MAXTG * 3) * 4);
  int*   tmD     = (int*)alloc((1 + MAXTD * 3) * 4);

  int n4x = T * EMB / 4;
  int n4g = NEXP * N_GU * EMB / 4;
  int n4d = NEXP * EMB * NH / 4;

  router_convx<<<T / 4 + 1024, 256, 0, stream>>>(x, xb, n4x, rw, rb, T, tokE, tokW);
  meta_convw<<<1 + 2048, 1024, 0, stream>>>(tokE, A, tmG, tmD, rowsArr, apos, guw, guwb, n4g);

  gemm_gate_up<<<GRID_GU + CONV_BLKS, 256, 0, stream>>>(xb, guwb, gub, rowsArr, tmG, hact,
                                                        dw, dwb, n4d);
  gemm_down<<<GRID_DN, 256, 0, stream>>>(hact, dwb, tmD, y);

  combine_out<<<(T * EMB / 4 + 255) / 256, 256, 0, stream>>>(y, db, tokE, tokW, apos, out, T);
}

// Round 18
// 133.280 us; speedup vs baseline: 1.2833x; 1.0007x over previous
//
#include <hip/hip_runtime.h>
#include <hip/hip_bf16.h>

#define EMB 1024
#define NEXP 8
#define NH 1024
#define N_GU 2048
#define TOPK 2

#define BK 64
#define KTILES 16      // 1024 / 64
#define BN 128

// gate_up: BM=128 (measured best at its grid size)
#define BMG 128
#define MAXTG 72
#define GRID_GU (MAXTG * 16)
#define CONV_BLKS 256   // converter-role blocks dispatched FIRST (overlap BW with MFMA, m114)

// down: BM=64 (measured best at its grid size)
#define BMD 64
#define MAXTD 160
#define GRID_DN (MAXTD * 8)

typedef __attribute__((ext_vector_type(4))) float f32x4;
typedef __attribute__((ext_vector_type(8))) short s16x8;
typedef __attribute__((ext_vector_type(4))) short s16x4;

typedef __attribute__((address_space(3))) unsigned int lds_u32;
typedef __attribute__((address_space(1))) const unsigned int glb_u32;

__device__ __forceinline__ void gl_lds16(const void* g, void* l) {
  __builtin_amdgcn_global_load_lds((glb_u32*)g, (lds_u32*)l, 16, 0, 0);
}

__device__ __forceinline__ unsigned short f2bf(float f) {
  union { float f; unsigned int u; } a; a.f = f;
  unsigned int u = a.u;
  unsigned int r = (u + 0x7FFFu + ((u >> 16) & 1u)) >> 16;
  return (unsigned short)r;
}

__device__ __forceinline__ float b2f(unsigned short h) {
  union { unsigned int u; float f; } a;
  a.u = ((unsigned int)h) << 16;
  return a.f;
}

// bijective chunked XCD swizzle (m204)
__device__ __forceinline__ int xcd_swz(int bid, int nwg) {
  int q = nwg >> 3, r = nwg & 7;
  int xcd = bid & 7, pos = bid >> 3;
  int base = (xcd < r) ? xcd * (q + 1) : r * (q + 1) + (xcd - r) * q;
  return base + pos;
}

// ---------------- dispatch 1: router + x fp32->bf16 ----------------
__global__ void router_convx(const float* __restrict__ x, unsigned short* __restrict__ xb, int n4x,
                             const float* __restrict__ rw, const float* __restrict__ rb, int T,
                             int* __restrict__ tokE, float* __restrict__ tokW) {
  int nr = T / 4;
  if ((int)blockIdx.x < nr) {
    int gwid = blockIdx.x * 4 + (threadIdx.x >> 6);
    int lane = threadIdx.x & 63;
    if (gwid >= T) return;
    const float* h = x + (size_t)gwid * EMB;
    float hreg[16];
    #pragma unroll
    for (int i = 0; i < 16; ++i) hreg[i] = h[lane + 64 * i];
    float sc[NEXP];
    #pragma unroll
    for (int e = 0; e < NEXP; ++e) {
      const float* w = rw + e * EMB;
      float s = 0.f;
      #pragma unroll
      for (int i = 0; i < 16; ++i) s += hreg[i] * w[lane + 64 * i];
      #pragma unroll
      for (int off = 32; off > 0; off >>= 1) s += __shfl_xor(s, off);
      sc[e] = s + rb[e];
    }
    if (lane == 0) {
      int e0 = 0; float v0 = sc[0];
      #pragma unroll
      for (int e = 1; e < NEXP; ++e) if (sc[e] > v0) { v0 = sc[e]; e0 = e; }
      int e1 = -1; float v1 = -3.0e38f;
      #pragma unroll
      for (int e = 0; e < NEXP; ++e) { if (e == e0) continue; if (sc[e] > v1) { v1 = sc[e]; e1 = e; } }
      float ex = __expf(v1 - v0);
      float w0 = 1.f / (1.f + ex);
      float w1 = ex / (1.f + ex);
      tokE[gwid * 2] = e0; tokE[gwid * 2 + 1] = e1;
      tokW[gwid * 2] = w0; tokW[gwid * 2 + 1] = w1;
    }
  } else {
    int base = (blockIdx.x - nr) * blockDim.x + threadIdx.x;
    int stride = (gridDim.x - nr) * blockDim.x;
    for (int i = base; i < n4x; i += stride) {
      float4 v = ((const float4*)x)[i];
      s16x4 o;
      o[0] = (short)f2bf(v.x);
      o[1] = (short)f2bf(v.y);
      o[2] = (short)f2bf(v.z);
      o[3] = (short)f2bf(v.w);
      ((s16x4*)xb)[i] = o;
    }
  }
}

// ---------------- dispatch 2: meta/scatter (block 0) || guw fp32->bf16 (rest) ----------------
__global__ void meta_convw(const int* __restrict__ tokE, int A,
                           int* __restrict__ tmG, int* __restrict__ tmD,
                           int* __restrict__ rows, int* __restrict__ apos,
                           const float* __restrict__ guw, unsigned short* __restrict__ guwb, int n4g) {
  if (blockIdx.x > 0) {
    int base = (blockIdx.x - 1) * blockDim.x + threadIdx.x;
    int stride = (gridDim.x - 1) * blockDim.x;
    for (int i = base; i < n4g; i += stride) {
      float4 v = ((const float4*)guw)[i];
      s16x4 o;
      o[0] = (short)f2bf(v.x);
      o[1] = (short)f2bf(v.y);
      o[2] = (short)f2bf(v.z);
      o[3] = (short)f2bf(v.w);
      ((s16x4*)guwb)[i] = o;
    }
    return;
  }
  __shared__ int hist[NEXP];
  __shared__ int offs[NEXP];
  __shared__ int fill[NEXP];
  int t = threadIdx.x;
  if (t < NEXP) { hist[t] = 0; fill[t] = 0; }
  __syncthreads();
  for (int i = t; i < A; i += blockDim.x) atomicAdd(&hist[tokE[i]], 1);
  __syncthreads();
  if (t == 0) {
    int off = 0, ntg = 0, ntd = 0;
    for (int e = 0; e < NEXP; ++e) {
      offs[e] = off;
      int c = hist[e];
      int ng = (c + BMG - 1) / BMG;
      for (int k = 0; k < ng; ++k) {
        tmG[1 + ntg * 3 + 0] = e;
        tmG[1 + ntg * 3 + 1] = off + k * BMG;
        tmG[1 + ntg * 3 + 2] = off + c;
        ntg++;
      }
      int nd = (c + BMD - 1) / BMD;
      for (int k = 0; k < nd; ++k) {
        tmD[1 + ntd * 3 + 0] = e;
        tmD[1 + ntd * 3 + 1] = off + k * BMD;
        tmD[1 + ntd * 3 + 2] = off + c;
        ntd++;
      }
      off += c;
    }
    tmG[0] = ntg;
    tmD[0] = ntd;
  }
  __syncthreads();
  for (int i = t; i < A; i += blockDim.x) {
    int e = tokE[i];
    int p = offs[e] + atomicAdd(&fill[e], 1);
    rows[p] = i >> 1;
    apos[i] = p;
  }
}

// ---------------- grouped GEMM 1 (128x128): gathered x @ gate_up_w[e]^T, fused SwiGLU ----------------
// R12/R15-proven plain 2-phase loop, single-buffer 32KB LDS, 4 blocks/CU.
// CONV_BLKS leading converter-role blocks: dw fp32->bf16, co-resident with GEMM from t=0
// so the BW work overlaps the MFMA phase (m114) instead of running as a serial tail.
__global__ __launch_bounds__(256, 4) void gemm_gate_up(
    const unsigned short* __restrict__ xb,
    const unsigned short* __restrict__ gub,
    const float* __restrict__ gu_bias,
    const int* __restrict__ rows,
    const int* __restrict__ tilemeta,
    unsigned short* __restrict__ hact,
    const float* __restrict__ dw, unsigned short* __restrict__ dwb, int n4d) {
  __shared__ __align__(16) short As[BMG * BK];
  __shared__ __align__(16) short Bs[BN * BK];
  if ((int)blockIdx.x < CONV_BLKS) {
    int base = (int)blockIdx.x * blockDim.x + threadIdx.x;
    int stride = CONV_BLKS * blockDim.x;
    for (int i = base; i < n4d; i += stride) {
      float4 v = ((const float4*)dw)[i];
      s16x4 o;
      o[0] = (short)f2bf(v.x);
      o[1] = (short)f2bf(v.y);
      o[2] = (short)f2bf(v.z);
      o[3] = (short)f2bf(v.w);
      ((s16x4*)dwb)[i] = o;
    }
    return;
  }
  int wg = xcd_swz(blockIdx.x - CONV_BLKS, GRID_GU);
  int tileid = wg >> 4;          // n = wg & 15 fast axis
  int n0 = (wg & 15) * BN;
  int nt = tilemeta[0];
  if (tileid >= nt) return;
  int e    = tilemeta[1 + tileid * 3 + 0];
  int m0   = tilemeta[1 + tileid * 3 + 1];
  int mEnd = tilemeta[1 + tileid * 3 + 2];

  int t = threadIdx.x;
  int lane = t & 63;
  int wid = t >> 6;
  int wr = wid >> 1, wc = wid & 1;

  int srow = lane >> 3;
  int scol = (((lane & 7) ^ (srow & 7)) * 8);
  const unsigned short* ga[4];
  const unsigned short* gb[4];
  int dstoff[4];
  #pragma unroll
  for (int q = 0; q < 4; ++q) {
    int rt = wid * 32 + q * 8 + srow;
    int ai = m0 + rt; if (ai >= mEnd) ai = mEnd - 1;
    ga[q] = xb + (size_t)rows[ai] * EMB + scol;
    gb[q] = gub + ((size_t)e * N_GU + n0 + rt) * EMB + scol;
    dstoff[q] = (wid * 32 + q * 8) * BK;
  }

  int fr = lane & 15;
  int q8 = (lane >> 4) * 8;
  int rsw = (fr & 7) << 3;

  f32x4 acc[4][4];
  #pragma unroll
  for (int i = 0; i < 4; ++i)
    #pragma unroll
    for (int j = 0; j < 4; ++j) acc[i][j] = (f32x4){0.f, 0.f, 0.f, 0.f};

  for (int tk = 0; tk < KTILES; ++tk) {
    int k0 = tk * BK;
    __syncthreads();
    #pragma unroll
    for (int q = 0; q < 4; ++q) {
      gl_lds16(ga[q] + k0, &As[dstoff[q]]);
      gl_lds16(gb[q] + k0, &Bs[dstoff[q]]);
    }
    __syncthreads();
    #pragma unroll
    for (int kk = 0; kk < BK; kk += 32) {
      s16x8 a[4], b[4];
      #pragma unroll
      for (int i = 0; i < 4; ++i)
        a[i] = *(const s16x8*)(&As[(wr * 64 + i * 16 + fr) * BK + ((kk + q8) ^ rsw)]);
      #pragma unroll
      for (int j = 0; j < 4; ++j)
        b[j] = *(const s16x8*)(&Bs[(wc * 64 + j * 16 + fr) * BK + ((kk + q8) ^ rsw)]);
      #pragma unroll
      for (int i = 0; i < 4; ++i)
        #pragma unroll
        for (int j = 0; j < 4; ++j)
          acc[i][j] = __builtin_amdgcn_mfma_f32_16x16x32_bf16(a[i], b[j], acc[i][j], 0, 0, 0);
    }
  }

  const float* bias_e = gu_bias + (size_t)e * N_GU;
  int rbase = m0 + wr * 64 + ((lane >> 4) * 4);
  #pragma unroll
  for (int i = 0; i < 4; ++i) {
    #pragma unroll
    for (int j = 0; j < 4; ++j) {
      int n = n0 + wc * 64 + j * 16 + fr;
      float v[4], o[4];
      #pragma unroll
      for (int r = 0; r < 4; ++r) v[r] = acc[i][j][r] + bias_e[n];
      #pragma unroll
      for (int r = 0; r < 4; ++r) o[r] = __shfl_xor(v[r], 1);
      if ((lane & 1) == 0) {
        int outc = n >> 1;
        #pragma unroll
        for (int r = 0; r < 4; ++r) {
          int pos = rbase + i * 16 + r;
          if (pos < mEnd) {
            float g = v[r], u = o[r];
            float gc = fminf(fmaxf(g, -7.f), 7.f);
            float uc = fminf(fmaxf(u, -7.f), 7.f);
            float sig = 1.f / (1.f + __expf(-1.702f * g));
            float act = gc * sig * (uc + 1.f);
            hact[(size_t)pos * NH + outc] = f2bf(act);
          }
        }
      }
    }
  }
}

// ---------------- grouped GEMM 2 (64x128): hact @ down_w[e]^T -> y (bf16) ----------------
__global__ __launch_bounds__(256, 6) void gemm_down(
    const unsigned short* __restrict__ hact,
    const unsigned short* __restrict__ dwb,
    const int* __restrict__ tilemeta,
    unsigned short* __restrict__ y) {
  __shared__ __align__(16) short As[BMD * BK];
  __shared__ __align__(16) short Bs[BN * BK];
  int wg = xcd_swz(blockIdx.x, gridDim.x);
  int tileid = wg >> 3;          // n = wg & 7 fast axis
  int n0 = (wg & 7) * BN;
  int nt = tilemeta[0];
  if (tileid >= nt) return;
  int e    = tilemeta[1 + tileid * 3 + 0];
  int m0   = tilemeta[1 + tileid * 3 + 1];
  int mEnd = tilemeta[1 + tileid * 3 + 2];

  int t = threadIdx.x;
  int lane = t & 63;
  int wid = t >> 6;
  int wr = wid >> 1, wc = wid & 1;

  int srow = lane >> 3;
  int scol = (((lane & 7) ^ (srow & 7)) * 8);
  const unsigned short* ga[2];
  const unsigned short* gb[4];
  int dstA[2], dstB[4];
  #pragma unroll
  for (int q = 0; q < 2; ++q) {
    int rt = q * 32 + wid * 8 + srow;
    int ai = m0 + rt; if (ai >= mEnd) ai = mEnd - 1;
    ga[q] = hact + (size_t)ai * NH + scol;
    dstA[q] = (q * 32 + wid * 8) * BK;
  }
  #pragma unroll
  for (int q = 0; q < 4; ++q) {
    int rt = q * 32 + wid * 8 + srow;
    gb[q] = dwb + ((size_t)e * EMB + n0 + rt) * NH + scol;
    dstB[q] = (q * 32 + wid * 8) * BK;
  }

  int fr = lane & 15;
  int q8 = (lane >> 4) * 8;
  int rsw = (fr & 7) << 3;

  f32x4 acc[2][4];
  #pragma unroll
  for (int i = 0; i < 2; ++i)
    #pragma unroll
    for (int j = 0; j < 4; ++j) acc[i][j] = (f32x4){0.f, 0.f, 0.f, 0.f};

  for (int tk = 0; tk < KTILES; ++tk) {
    int k0 = tk * BK;
    __syncthreads();
    #pragma unroll
    for (int q = 0; q < 2; ++q) gl_lds16(ga[q] + k0, &As[dstA[q]]);
    #pragma unroll
    for (int q = 0; q < 4; ++q) gl_lds16(gb[q] + k0, &Bs[dstB[q]]);
    __syncthreads();
    #pragma unroll
    for (int kk = 0; kk < BK; kk += 32) {
      s16x8 a[2], b[4];
      #pragma unroll
      for (int i = 0; i < 2; ++i)
        a[i] = *(const s16x8*)(&As[(wr * 32 + i * 16 + fr) * BK + ((kk + q8) ^ rsw)]);
      #pragma unroll
      for (int j = 0; j < 4; ++j)
        b[j] = *(const s16x8*)(&Bs[(wc * 64 + j * 16 + fr) * BK + ((kk + q8) ^ rsw)]);
      #pragma unroll
      for (int i = 0; i < 2; ++i)
        #pragma unroll
        for (int j = 0; j < 4; ++j)
          acc[i][j] = __builtin_amdgcn_mfma_f32_16x16x32_bf16(a[i], b[j], acc[i][j], 0, 0, 0);
    }
  }

  int rbase = m0 + wr * 32 + ((lane >> 4) * 4);
  #pragma unroll
  for (int i = 0; i < 2; ++i) {
    #pragma unroll
    for (int j = 0; j < 4; ++j) {
      int n = n0 + wc * 64 + j * 16 + fr;
      #pragma unroll
      for (int r = 0; r < 4; ++r) {
        int pos = rbase + i * 16 + r;
        if (pos < mEnd) y[(size_t)pos * EMB + n] = f2bf(acc[i][j][r]);
      }
    }
  }
}

// ---------------- final combine (bf16 y) ----------------
__global__ void combine_out(const unsigned short* __restrict__ y, const float* __restrict__ down_b,
                            const int* __restrict__ tokE, const float* __restrict__ tokW,
                            const int* __restrict__ apos, float* __restrict__ out, int T) {
  int i = blockIdx.x * blockDim.x + threadIdx.x;
  int tot = T * (EMB / 4);
  if (i >= tot) return;
  int tok = i >> 8;
  int c = i & 255;
  int e0 = tokE[tok * 2], e1 = tokE[tok * 2 + 1];
  float w0 = tokW[tok * 2], w1 = tokW[tok * 2 + 1];
  int p0 = apos[tok * 2], p1 = apos[tok * 2 + 1];
  s16x4 v0 = ((const s16x4*)(y + (size_t)p0 * EMB))[c];
  s16x4 v1 = ((const s16x4*)(y + (size_t)p1 * EMB))[c];
  float4 b0 = ((const float4*)(down_b + (size_t)e0 * EMB))[c];
  float4 b1 = ((const float4*)(down_b + (size_t)e1 * EMB))[c];
  float4 o;
  o.x = w0 * (b2f((unsigned short)v0[0]) + b0.x) + w1 * (b2f((unsigned short)v1[0]) + b1.x);
  o.y = w0 * (b2f((unsigned short)v0[1]) + b0.y) + w1 * (b2f((unsigned short)v1[1]) + b1.y);
  o.z = w0 * (b2f((unsigned short)v0[2]) + b0.z) + w1 * (b2f((unsigned short)v1[2]) + b1.z);
  o.w = w0 * (b2f((unsigned short)v0[3]) + b0.w) + w1 * (b2f((unsigned short)v1[3]) + b1.w);
  ((float4*)out)[i] = o;
}

extern "C" void kernel_launch(void* const* d_in, const int* in_sizes, int n_in,
                              void* d_out, int out_size, void* d_ws, size_t ws_size,
                              hipStream_t stream) {
  const float* x   = (const float*)d_in[0];
  const float* rw  = (const float*)d_in[1];
  const float* rb  = (const float*)d_in[2];
  const float* guw = (const float*)d_in[3];
  const float* gub = (const float*)d_in[4];
  const float* dw  = (const float*)d_in[5];
  const float* db  = (const float*)d_in[6];
  float* out = (float*)d_out;

  int T = in_sizes[0] / EMB;   // 4096
  int A = T * TOPK;            // 8192

  char* ws = (char*)d_ws;
  size_t off = 0;
  auto alloc = [&](size_t bytes) -> void* {
    void* p = ws + off;
    off = (off + bytes + 255) & ~((size_t)255);
    return p;
  };
  unsigned short* xb   = (unsigned short*)alloc((size_t)T * EMB * 2);
  unsigned short* guwb = (unsigned short*)alloc((size_t)NEXP * N_GU * EMB * 2);
  unsigned short* dwb  = (unsigned short*)alloc((size_t)NEXP * EMB * NH * 2);
  unsigned short* hact = (unsigned short*)alloc((size_t)A * NH * 2);
  unsigned short* y    = (unsigned short*)alloc((size_t)A * EMB * 2);
  int*   tokE    = (int*)alloc((size_t)A * 4);
  float* tokW    = (float*)alloc((size_t)A * 4);
  int*   apos    = (int*)alloc((size_t)A * 4);
  int*   rowsArr = (int*)alloc((size_t)A * 4);
  int*   tmG     = (int*)alloc((1 + MAXTG * 3) * 4);
  int*   tmD     = (int*)alloc((1 + MAXTD * 3) * 4);

  int n4x = T * EMB / 4;
  int n4g = NEXP * N_GU * EMB / 4;
  int n4d = NEXP * EMB * NH / 4;

  router_convx<<<T / 4 + 1024, 256, 0, stream>>>(x, xb, n4x, rw, rb, T, tokE, tokW);
  meta_convw<<<1 + 2048, 1024, 0, stream>>>(tokE, A, tmG, tmD, rowsArr, apos, guw, guwb, n4g);

  gemm_gate_up<<<CONV_BLKS + GRID_GU, 256, 0, stream>>>(xb, guwb, gub, rowsArr, tmG, hact,
                                                        dw, dwb, n4d);
  gemm_down<<<GRID_DN, 256, 0, stream>>>(hact, dwb, tmD, y);

  combine_out<<<(T * EMB / 4 + 255) / 256, 256, 0, stream>>>(y, db, tokE, tokW, apos, out, T);
}